// Round 10
// baseline (189.019 us; speedup 1.0000x reference)
//
#include <hip/hip_runtime.h>

#define N_PTS 81920
#define M_PTS 20000
#define NC 13
#define NCELLS 2197
#define CELLW 0.7692307692f
#define INVCELL 1.3f
#define BIGF 3.0e38f
#define CAP_STAGE 320
#define CAND_CAP 328
#define CHUNKS 8
#define PPC 16   // points per chunk (x 4 subs = 64 lanes)

__device__ __forceinline__ int clampi(int v, int lo, int hi) {
  return v < lo ? lo : (v > hi ? hi : v);
}
__device__ __forceinline__ int cell_coord(float p) {
  return clampi((int)(p * INVCELL), 0, NC - 1);
}
__device__ __forceinline__ float floorpack(float d) {
  return __uint_as_float(__float_as_uint(d) & 0xFFFF8000u);
}

// ---- setup kernels ----

__global__ void hist_both_kernel(const float* __restrict__ y, const float* __restrict__ x,
                                 int* __restrict__ ycnt, int* __restrict__ xcnt) {
  int i = blockIdx.x * blockDim.x + threadIdx.x;
  if (i < M_PTS) {
    int c = (cell_coord(y[3*i+2])*NC + cell_coord(y[3*i+1]))*NC + cell_coord(y[3*i]);
    atomicAdd(&ycnt[c], 1);
  } else {
    int j = i - M_PTS;
    if (j < N_PTS) {
      int c = (cell_coord(x[3*j+2])*NC + cell_coord(x[3*j+1]))*NC + cell_coord(x[3*j]);
      atomicAdd(&xcnt[c], 1);
    }
  }
}

__global__ void scan2_kernel(const int* __restrict__ ycnt, int* __restrict__ ystart, int* __restrict__ ycur,
                             const int* __restrict__ xcnt, int* __restrict__ xstart, int* __restrict__ xcur) {
  const int* cnt = (blockIdx.x == 0) ? ycnt : xcnt;
  int* start     = (blockIdx.x == 0) ? ystart : xstart;
  int* cursor    = (blockIdx.x == 0) ? ycur : xcur;
  __shared__ int tmp[1024];
  int tid = threadIdx.x;
  int chunk = (NCELLS + 1023) >> 10;
  int base = tid * chunk;
  int sum = 0;
  for (int k = 0; k < chunk; ++k) {
    int j = base + k;
    if (j < NCELLS) sum += cnt[j];
  }
  tmp[tid] = sum;
  __syncthreads();
  for (int off = 1; off < 1024; off <<= 1) {
    int v = (tid >= off) ? tmp[tid - off] : 0;
    __syncthreads();
    tmp[tid] += v;
    __syncthreads();
  }
  int run = tmp[tid] - sum;
  for (int k = 0; k < chunk; ++k) {
    int j = base + k;
    if (j < NCELLS) { start[j] = run; cursor[j] = run; run += cnt[j]; }
  }
  if (tid == 1023) start[NCELLS] = tmp[1023];
}

__global__ void scatter_both_kernel(const float* __restrict__ y, const float* __restrict__ x,
                                    int* __restrict__ ycur, int* __restrict__ xcur,
                                    float4* __restrict__ ys4, int* __restrict__ xorder,
                                    float4* __restrict__ xs4) {
  int i = blockIdx.x * blockDim.x + threadIdx.x;
  if (i < M_PTS) {
    float px = y[3*i], py = y[3*i+1], pz = y[3*i+2];
    int c = (cell_coord(pz)*NC + cell_coord(py))*NC + cell_coord(px);
    int pos = atomicAdd(&ycur[c], 1);
    ys4[pos] = make_float4(px, py, pz, __int_as_float(i));
  } else {
    int j = i - M_PTS;
    if (j < N_PTS) {
      float px = x[3*j], py = x[3*j+1], pz = x[3*j+2];
      int c = (cell_coord(pz)*NC + cell_coord(py))*NC + cell_coord(px);
      int pos = atomicAdd(&xcur[c], 1);
      xorder[pos] = j;
      if (xs4) xs4[pos] = make_float4(px, py, pz, __int_as_float(j));
    }
  }
}

// (fused/brute fallback only) determinism: in-cell sort by original index
__global__ void sortcell_kernel(float4* __restrict__ ys4, const int* __restrict__ ystart) {
  int c = blockIdx.x * blockDim.x + threadIdx.x;
  if (c >= NCELLS) return;
  int r0 = ystart[c], r1 = ystart[c+1];
  for (int i = r0 + 1; i < r1; ++i) {
    float4 v = ys4[i];
    int key = __float_as_int(v.w);
    int j = i - 1;
    while (j >= r0 && __float_as_int(ys4[j].w) > key) { ys4[j+1] = ys4[j]; --j; }
    ys4[j+1] = v;
  }
}

// sort a bitonic 16-sequence ascending (valid only for bitonic input)
__device__ __forceinline__ void bitonic_sort16(float (&d)[16]) {
  #define CE(a,b) { float lo=fminf(d[a],d[b]); float hi=fmaxf(d[a],d[b]); d[a]=lo; d[b]=hi; }
  CE(0,8) CE(1,9) CE(2,10) CE(3,11) CE(4,12) CE(5,13) CE(6,14) CE(7,15)
  CE(0,4) CE(1,5) CE(2,6) CE(3,7) CE(8,12) CE(9,13) CE(10,14) CE(11,15)
  CE(0,2) CE(1,3) CE(4,6) CE(5,7) CE(8,10) CE(9,11) CE(12,14) CE(13,15)
  CE(0,1) CE(2,3) CE(4,5) CE(6,7) CE(8,9) CE(10,11) CE(12,13) CE(14,15)
  #undef CE
}

// branchless sorted insert into ascending 16-list; ~31 VALU ops
__device__ __forceinline__ void ins16(float (&s)[16], float k) {
  #pragma unroll
  for (int j = 15; j >= 1; --j) s[j] = fminf(fmaxf(s[j-1], k), s[j]);
  s[0] = fminf(s[0], k);
}

// ---- split path kernel A: kNN, block-per-(cell,chunk), TPP=4, LDS staging ----
// key = (d_bits & 0xFFFF8000) | id  (d>0 -> float order == bit order; id<2^15).
// Dual independent per-lane lists (ILP) + prefetch hide LDS latency; the exact
// per-lane top-16 is recovered by an in-lane bitonic merge, and the group's
// exact union top-16 by a 4-lane bitonic merge -> identical selection to TPP=1,
// scan-order independent, replay-deterministic.
__global__ void __launch_bounds__(64) knn_cell_kernel(
    const float4* __restrict__ xs4,
    const float4* __restrict__ ys4, const int* __restrict__ ystart,
    const int* __restrict__ xstart,
    unsigned short* __restrict__ pi)
{
  int bid = blockIdx.x;                 // grid = NCELLS*CHUNKS
  int c = bid / CHUNKS, chunk = bid % CHUNKS;
  int cbeg = xstart[c];
  int cend = xstart[c+1];
  int pbeg = cbeg + chunk*PPC;
  int pend = min(cend, pbeg + PPC);
  if (pbeg >= pend) return;             // uniform across block

  int ccx = c % NC, ccy = (c / NC) % NC, ccz = c / (NC*NC);
  int x0 = ccx-1 < 0 ? 0 : ccx-1, x1 = ccx+1 > NC-1 ? NC-1 : ccx+1;
  int y0 = ccy-1 < 0 ? 0 : ccy-1, y1 = ccy+1 > NC-1 ? NC-1 : ccy+1;
  int z0 = ccz-1 < 0 ? 0 : ccz-1, z1 = ccz+1 > NC-1 ? NC-1 : ccz+1;

  __shared__ float4 cand[CAND_CAP];
  int tid = threadIdx.x;

  // stage clamped 3x3x3 region (rows are contiguous ys4 slices; uniform addrs)
  int off = 0, nst = 0; bool ovf = false;
  for (int gz = z0; gz <= z1; ++gz) {
    for (int gy = y0; gy <= y1; ++gy) {
      int rowbase = (gz*NC + gy)*NC;
      int r0 = ystart[rowbase + x0];
      int r1 = ystart[rowbase + x1 + 1];
      int len = r1 - r0;
      if (!ovf && off + len <= CAP_STAGE) {
        for (int k = tid; k < len; k += 64) cand[off + k] = ys4[r0 + k];
        off += len; ++nst;
      } else ovf = true;
    }
  }
  int L = off;
  int Lp = (L + 7) & ~7;
  if (Lp < 8) Lp = 8;
  // pad with +huge sentinels so the pipelined loop needs no tail handling
  for (int k = tid; k < Lp - L; k += 64) cand[L + k] = make_float4(1e18f, 1e18f, 1e18f, 0.0f);
  __syncthreads();

  int g = tid >> 2, sub = tid & 3;
  int pidx = pbeg + g;
  bool active = pidx < pend;
  int gid = active ? pidx : (pend - 1);   // inactive groups dup last point
  float4 xq = xs4[gid];
  float xpx = xq.x, xpy = xq.y, xpz = xq.z;

  auto packkey = [&](float4 q) -> float {
    float dx = xpx - q.x, dy = xpy - q.y, dz = xpz - q.z;
    float d = fmaf(dx, dx, fmaf(dy, dy, dz*dz));
    unsigned kb = (__float_as_uint(d) & 0xFFFF8000u) | (__float_as_uint(q.w) & 0x7FFFu);
    return __uint_as_float(kb);
  };

  // staged scan: dual independent lists + prefetch (4 LDS loads in flight)
  float sA[16], sB[16];
  #pragma unroll
  for (int j = 0; j < 16; ++j) { sA[j] = BIGF; sB[j] = BIGF; }
  {
    float4 p0 = cand[sub], p1 = cand[sub + 4];
    int i = sub;
    for (; i + 8 < Lp; i += 8) {
      float4 n0 = cand[i + 8], n1 = cand[i + 12];
      ins16(sA, packkey(p0));
      ins16(sB, packkey(p1));
      p0 = n0; p1 = n1;
    }
    ins16(sA, packkey(p0));
    ins16(sB, packkey(p1));
  }

  // in-lane exact merge of the two sorted lists -> lane's true top-16
  float s[16];
  #pragma unroll
  for (int i = 0; i < 16; ++i) s[i] = fminf(sA[i], sB[15 - i]);
  bitonic_sort16(s);

  // exact union top-16 across the 4 subs of this group (identical in all 4 lanes)
  auto merged16 = [&](float (&u)[16]) {
    float cb[16];
    #pragma unroll
    for (int i = 0; i < 16; ++i) cb[i] = fminf(s[i], __shfl_xor(s[15-i], 1));
    bitonic_sort16(cb);
    #pragma unroll
    for (int i = 0; i < 16; ++i) u[i] = fminf(cb[i], __shfl_xor(cb[15-i], 2));
    bitonic_sort16(u);
  };

  auto scan_row_g = [&](int xa, int xb, int rowbase) {
    int r0 = ystart[rowbase + xa];
    int r1 = ystart[rowbase + xb + 1];
    int i = r0 + sub;
    for (; i + 4 < r1; i += 8) {
      float4 q0 = ys4[i], q1 = ys4[i+4];
      float k0 = packkey(q0), k1 = packkey(q1);
      ins16(s, k0); ins16(s, k1);
    }
    for (; i < r1; i += 4) ins16(s, packkey(ys4[i]));
  };

  if (ovf) { // staged prefix only; scan remaining region rows from global (rare)
    int cnt2 = 0;
    for (int gz = z0; gz <= z1; ++gz)
      for (int gy = y0; gy <= y1; ++gy) {
        if (cnt2 >= nst) scan_row_g(x0, x1, (gz*NC + gy)*NC);
        ++cnt2;
      }
  }

  // ring expansion (exact in key space) with row/cell culling vs merged 16th
  float u[16];
  merged16(u);
  float s15m = u[15];
  int R = 1;
  while (true) {
    float b = BIGF;
    if (ccx - R >= 0)    b = fminf(b, xpx - (float)(ccx-R)*CELLW);
    if (ccx + R <= NC-2) b = fminf(b, (float)(ccx+R+1)*CELLW - xpx);
    if (ccy - R >= 0)    b = fminf(b, xpy - (float)(ccy-R)*CELLW);
    if (ccy + R <= NC-2) b = fminf(b, (float)(ccy+R+1)*CELLW - xpy);
    if (ccz - R >= 0)    b = fminf(b, xpz - (float)(ccz-R)*CELLW);
    if (ccz + R <= NC-2) b = fminf(b, (float)(ccz+R+1)*CELLW - xpz);
    b = fmaxf(b - 1e-4f, 0.0f);          // conservative vs binning rounding
    if (s15m <= floorpack(b*b) || R >= NC) break;
    ++R;
    int z0r = ccz-R < 0 ? 0 : ccz-R, z1r = ccz+R > NC-1 ? NC-1 : ccz+R;
    int y0r = ccy-R < 0 ? 0 : ccy-R, y1r = ccy+R > NC-1 ? NC-1 : ccy+R;
    int x0r = ccx-R < 0 ? 0 : ccx-R, x1r = ccx+R > NC-1 ? NC-1 : ccx+R;
    for (int gz = z0r; gz <= z1r; ++gz) {
      int dzz = gz - ccz; if (dzz < 0) dzz = -dzz;
      float gapz = (gz > ccz) ? ((float)gz*CELLW - xpz)
                 : ((gz < ccz) ? (xpz - (float)(gz+1)*CELLW) : 0.0f);
      gapz = fmaxf(gapz - 1e-4f, 0.0f);
      float gz2 = gapz * gapz;
      for (int gy = y0r; gy <= y1r; ++gy) {
        int dyy = gy - ccy; if (dyy < 0) dyy = -dyy;
        float gapy = (gy > ccy) ? ((float)gy*CELLW - xpy)
                   : ((gy < ccy) ? (xpy - (float)(gy+1)*CELLW) : 0.0f);
        gapy = fmaxf(gapy - 1e-4f, 0.0f);
        float rowd2 = fmaf(gapy, gapy, gz2);
        if (floorpack(rowd2) >= s15m) continue;   // row can't beat union 16th
        int rowbase = (gz*NC + gy)*NC;
        if (dzz == R || dyy == R) {
          scan_row_g(x0r, x1r, rowbase);
        } else {
          if (ccx - R >= 0) {
            float gapx = fmaxf(xpx - (float)(ccx-R+1)*CELLW - 1e-4f, 0.0f);
            if (floorpack(fmaf(gapx, gapx, rowd2)) < s15m)
              scan_row_g(ccx-R, ccx-R, rowbase);
          }
          if (ccx + R <= NC-1) {
            float gapx = fmaxf((float)(ccx+R)*CELLW - xpx - 1e-4f, 0.0f);
            if (floorpack(fmaf(gapx, gapx, rowd2)) < s15m)
              scan_row_g(ccx+R, ccx+R, rowbase);
          }
        }
      }
    }
    merged16(u);
    s15m = u[15];
  }

  if (active) {  // each sub writes 4 u16 ids of the sorted union (8B store)
    float v0 = u[sub*4+0], v1 = u[sub*4+1], v2 = u[sub*4+2], v3 = u[sub*4+3];
    unsigned wlo = (__float_as_uint(v0) & 0x7FFFu) | ((__float_as_uint(v1) & 0x7FFFu) << 16);
    unsigned whi = (__float_as_uint(v2) & 0x7FFFu) | ((__float_as_uint(v3) & 0x7FFFu) << 16);
    uint2 W; W.x = wlo; W.y = whi;
    ((uint2*)pi)[gid*4 + sub] = W;
  }
}

// ---- split path kernel B: MLP, one lane per (point, neighbor) ----
template<int CTRL>
__device__ __forceinline__ float ror_add(float v) {
  int r = __builtin_amdgcn_update_dpp(0, __float_as_int(v), CTRL, 0xF, 0xF, true);
  return v + __int_as_float(r);
}
__device__ __forceinline__ float red16(float v) {
  v = ror_add<0x121>(v);   // row_ror:1
  v = ror_add<0x122>(v);   // row_ror:2
  v = ror_add<0x124>(v);   // row_ror:4
  v = ror_add<0x128>(v);   // row_ror:8
  return v;                // every lane of the 16-row holds the 16-lane sum
}

__global__ void __launch_bounds__(256) mlp_kernel(
    const float* __restrict__ yat, const float4* __restrict__ xs4, const float* __restrict__ y,
    const float* __restrict__ W1, const float* __restrict__ b1,
    const float* __restrict__ W2, const float* __restrict__ b2,
    const float* __restrict__ W3, const float* __restrict__ b3,
    const float* __restrict__ g1, const float* __restrict__ be1,
    const float* __restrict__ m1, const float* __restrict__ v1,
    const float* __restrict__ g2, const float* __restrict__ be2,
    const float* __restrict__ m2, const float* __restrict__ v2,
    const unsigned short* __restrict__ pi, float* __restrict__ out)
{
  int t = threadIdx.x;
  int o = t & 15;                              // lane's neighbor slot / out channel
  int gid = (blockIdx.x * 256 + t) >> 4;       // grid = N_PTS*16 threads
  float4 xq = xs4[gid];                        // broadcast within group
  int p = __float_as_int(xq.w);

  int id = (int)pi[gid*16 + o];                // 32B per group, coalesced
  // recompute exact squared distance (selection used truncated keys)
  float dx = xq.x - y[3*id], dy = xq.y - y[3*id+1], dz = xq.z - y[3*id+2];
  float dist = fmaf(dx, dx, fmaf(dy, dy, dz*dz));
  float invd = 1.0f / dist;                    // feature = 1/(squared dist)

  const float4* a4 = (const float4*)(yat + ((size_t)id << 4));
  float4 q0 = a4[0], q1 = a4[1], q2 = a4[2], q3 = a4[3];
  float a[16];
  a[0]=q0.x; a[1]=q0.y; a[2]=q0.z; a[3]=q0.w;
  a[4]=q1.x; a[5]=q1.y; a[6]=q1.z; a[7]=q1.w;
  a[8]=q2.x; a[9]=q2.y; a[10]=q2.z; a[11]=q2.w;
  a[12]=q3.x; a[13]=q3.y; a[14]=q3.z; a[15]=q3.w;

  // layer 1 (+leaky+BN1); weight indices compile-time -> wave-uniform loads
  float h[16];
  #pragma unroll
  for (int oo = 0; oo < 16; ++oo) {
    float acc = fmaf(invd, W1[256 + oo], b1[oo]);
    #pragma unroll
    for (int i = 0; i < 16; ++i) acc = fmaf(a[i], W1[i*16 + oo], acc);
    acc = fmaxf(acc, 0.2f * acc);              // leaky_relu(0.2)
    float S = g1[oo] * rsqrtf(v1[oo] + 1e-5f);
    h[oo] = fmaf(acc - m1[oo], S, be1[oo]);    // BN1
  }

  // layer 2 (+leaky+BN2)
  float f2[16];
  #pragma unroll
  for (int oo = 0; oo < 16; ++oo) {
    float acc = b2[oo];
    #pragma unroll
    for (int i = 0; i < 16; ++i) acc = fmaf(h[i], W2[i*16 + oo], acc);
    acc = fmaxf(acc, 0.2f * acc);
    float S = g2[oo] * rsqrtf(v2[oo] + 1e-5f);
    f2[oo] = fmaf(acc - m2[oo], S, be2[oo]);
  }

  // final layer fused with cross-neighbor DPP reduction; lane owns channel o
  float acc = b3[o];
  #pragma unroll
  for (int i = 0; i < 16; ++i) acc = fmaf(red16(h[i]),  W3[i*16 + o], acc);
  #pragma unroll
  for (int i = 0; i < 16; ++i) acc = fmaf(red16(f2[i]), W3[(16 + i)*16 + o], acc);

  out[(size_t)p*16 + o] = acc;                 // 64B per group, coalesced
}

// ---- fallback 1: fused kernel (only if ws too small for split path) ----
__device__ __forceinline__ void stage_weights(float* lds, int t,
    const float* W1, const float* b1, const float* W2, const float* b2,
    const float* W3, const float* b3,
    const float* g1, const float* be1, const float* m1, const float* v1,
    const float* g2, const float* be2, const float* m2, const float* v2)
{
  for (int k = t; k < 272; k += 256) { int i = k >> 4, o = k & 15; lds[o*20 + i] = W1[k]; }
  for (int k = t; k < 256; k += 256) { int i = k >> 4, o = k & 15; lds[320 + o*16 + i] = W2[k]; }
  for (int k = t; k < 512; k += 256) { int i = k >> 4, o = k & 15; lds[576 + o*32 + i] = W3[k]; }
  if (t < 16) {
    lds[1088 + t] = b1[t];
    lds[1104 + t] = b2[t];
    lds[1120 + t] = b3[t];
    float s1 = g1[t] * rsqrtf(v1[t] + 1e-5f);
    lds[1136 + t] = s1;
    lds[1152 + t] = be1[t] - m1[t]*s1;
    float s2 = g2[t] * rsqrtf(v2[t] + 1e-5f);
    lds[1168 + t] = s2;
    lds[1184 + t] = be2[t] - m2[t]*s2;
  }
}

__device__ __forceinline__ void topk_insert(float (&s)[16], int (&si)[16], float d, int qi) {
  #pragma unroll
  for (int j = 15; j >= 1; --j) {
    bool c1 = d < s[j-1];
    bool c2 = d < s[j];
    float ns = c1 ? s[j-1] : (c2 ? d : s[j]);
    int  ni = c1 ? si[j-1] : (c2 ? qi : si[j]);
    s[j] = ns; si[j] = ni;
  }
  if (d < s[0]) { si[0] = qi; s[0] = d; }
}

__device__ __forceinline__ void mlp_and_store(const float* lds, const float2* spill, int t,
    const float* __restrict__ yat, float* __restrict__ out, int p)
{
  const float* W1t = lds;
  const float* W2t = lds + 320;
  const float* W3t = lds + 576;
  const float* sb1 = lds + 1088;
  const float* sb2 = lds + 1104;
  const float* sb3 = lds + 1120;
  const float* S1 = lds + 1136;
  const float* T1 = lds + 1152;
  const float* S2 = lds + 1168;
  const float* T2 = lds + 1184;

  float fx1[16], fx2[16];
  #pragma unroll
  for (int o = 0; o < 16; ++o) { fx1[o] = 0.0f; fx2[o] = 0.0f; }

  #pragma unroll 1
  for (int j = 0; j < 16; ++j) {
    float2 sv = spill[j*256 + t];
    float invd = 1.0f / sv.x;
    int id = __float_as_int(sv.y);
    const float4* a4 = (const float4*)(yat + ((size_t)id << 4));
    float4 q0 = a4[0], q1 = a4[1], q2 = a4[2], q3 = a4[3];
    float a[16];
    a[0]=q0.x; a[1]=q0.y; a[2]=q0.z; a[3]=q0.w;
    a[4]=q1.x; a[5]=q1.y; a[6]=q1.z; a[7]=q1.w;
    a[8]=q2.x; a[9]=q2.y; a[10]=q2.z; a[11]=q2.w;
    a[12]=q3.x; a[13]=q3.y; a[14]=q3.z; a[15]=q3.w;
    float h[16];
    #pragma unroll
    for (int o = 0; o < 16; ++o) {
      float acc = fmaf(invd, W1t[o*20 + 16], sb1[o]);
      #pragma unroll
      for (int i = 0; i < 16; ++i) acc = fmaf(a[i], W1t[o*20 + i], acc);
      acc = fmaxf(acc, 0.2f * acc);
      float hv = fmaf(acc, S1[o], T1[o]);
      h[o] = hv;
      fx1[o] += hv;
    }
    #pragma unroll
    for (int o = 0; o < 16; ++o) {
      float acc = sb2[o];
      #pragma unroll
      for (int i = 0; i < 16; ++i) acc = fmaf(h[i], W2t[o*16 + i], acc);
      acc = fmaxf(acc, 0.2f * acc);
      fx2[o] += fmaf(acc, S2[o], T2[o]);
    }
  }

  float res[16];
  #pragma unroll
  for (int o = 0; o < 16; ++o) {
    float acc = sb3[o];
    #pragma unroll
    for (int i = 0; i < 16; ++i) acc = fmaf(fx1[i], W3t[o*32 + i], acc);
    #pragma unroll
    for (int i = 0; i < 16; ++i) acc = fmaf(fx2[i], W3t[o*32 + 16 + i], acc);
    res[o] = acc;
  }
  float* op = out + ((size_t)p << 4);
  float4 r;
  r.x=res[0]; r.y=res[1]; r.z=res[2]; r.w=res[3];   ((float4*)op)[0] = r;
  r.x=res[4]; r.y=res[5]; r.z=res[6]; r.w=res[7];   ((float4*)op)[1] = r;
  r.x=res[8]; r.y=res[9]; r.z=res[10]; r.w=res[11]; ((float4*)op)[2] = r;
  r.x=res[12]; r.y=res[13]; r.z=res[14]; r.w=res[15];((float4*)op)[3] = r;
}

__global__ void __launch_bounds__(256) knn_mlp_fused_kernel(
    const float* __restrict__ x, const float* __restrict__ yat,
    const float* __restrict__ W1, const float* __restrict__ b1,
    const float* __restrict__ W2, const float* __restrict__ b2,
    const float* __restrict__ W3, const float* __restrict__ b3,
    const float* __restrict__ g1, const float* __restrict__ be1,
    const float* __restrict__ m1, const float* __restrict__ v1,
    const float* __restrict__ g2, const float* __restrict__ be2,
    const float* __restrict__ m2, const float* __restrict__ v2,
    const float4* __restrict__ ys4, const int* __restrict__ ystart,
    const int* __restrict__ xorder, float* __restrict__ out)
{
  __shared__ float lds[1200];
  __shared__ float2 spill[4096];
  int t = threadIdx.x;
  stage_weights(lds, t, W1,b1,W2,b2,W3,b3, g1,be1,m1,v1, g2,be2,m2,v2);
  __syncthreads();

  int gid = blockIdx.x * 256 + t;
  int p = xorder[gid];
  float xpx = x[3*p], xpy = x[3*p+1], xpz = x[3*p+2];
  int cx = cell_coord(xpx), cy = cell_coord(xpy), cz = cell_coord(xpz);

  float s[16]; int si[16];
  #pragma unroll
  for (int j = 0; j < 16; ++j) { s[j] = BIGF; si[j] = 0; }

  auto scan_row = [&](int gz, int gy, int xa, int xb) {
    int rowbase = (gz*NC + gy)*NC;
    int r0 = ystart[rowbase + xa];
    int r1 = ystart[rowbase + xb + 1];
    for (int i = r0; i < r1; ++i) {
      float4 q = ys4[i];
      float dx = xpx - q.x, dy = xpy - q.y, dz = xpz - q.z;
      float d = fmaf(dx, dx, fmaf(dy, dy, dz*dz));
      if (d < s[15]) topk_insert(s, si, d, __float_as_int(q.w));
    }
  };

  {
    int z0 = cz-1 < 0 ? 0 : cz-1, z1 = cz+1 > NC-1 ? NC-1 : cz+1;
    int y0 = cy-1 < 0 ? 0 : cy-1, y1 = cy+1 > NC-1 ? NC-1 : cy+1;
    int x0 = cx-1 < 0 ? 0 : cx-1, x1 = cx+1 > NC-1 ? NC-1 : cx+1;
    for (int gz = z0; gz <= z1; ++gz)
      for (int gy = y0; gy <= y1; ++gy)
        scan_row(gz, gy, x0, x1);
  }

  int R = 1;
  while (true) {
    float b = BIGF;
    if (cx - R >= 0)    b = fminf(b, xpx - (float)(cx-R)*CELLW);
    if (cx + R <= NC-2) b = fminf(b, (float)(cx+R+1)*CELLW - xpx);
    if (cy - R >= 0)    b = fminf(b, xpy - (float)(cy-R)*CELLW);
    if (cy + R <= NC-2) b = fminf(b, (float)(cy+R+1)*CELLW - xpy);
    if (cz - R >= 0)    b = fminf(b, xpz - (float)(cz-R)*CELLW);
    if (cz + R <= NC-2) b = fminf(b, (float)(cz+R+1)*CELLW - xpz);
    b = fmaxf(b - 1e-4f, 0.0f);
    if (s[15] <= b*b || R >= NC) break;
    ++R;
    int z0 = cz-R < 0 ? 0 : cz-R, z1 = cz+R > NC-1 ? NC-1 : cz+R;
    int y0 = cy-R < 0 ? 0 : cy-R, y1 = cy+R > NC-1 ? NC-1 : cy+R;
    int x0 = cx-R < 0 ? 0 : cx-R, x1 = cx+R > NC-1 ? NC-1 : cx+R;
    for (int gz = z0; gz <= z1; ++gz) {
      int dzz = gz - cz; if (dzz < 0) dzz = -dzz;
      for (int gy = y0; gy <= y1; ++gy) {
        int dyy = gy - cy; if (dyy < 0) dyy = -dyy;
        if (dzz == R || dyy == R) {
          scan_row(gz, gy, x0, x1);
        } else {
          if (cx - R >= 0)    scan_row(gz, gy, cx-R, cx-R);
          if (cx + R <= NC-1) scan_row(gz, gy, cx+R, cx+R);
        }
      }
    }
  }

  #pragma unroll
  for (int j = 0; j < 16; ++j) spill[j*256 + t] = make_float2(s[j], __int_as_float(si[j]));
  mlp_and_store(lds, spill, t, yat, out, p);
}

// ---- fallback 2: brute force (no workspace needed) ----
__global__ void __launch_bounds__(256) brute_kernel(
    const float* __restrict__ x, const float* __restrict__ y, const float* __restrict__ yat,
    const float* __restrict__ W1, const float* __restrict__ b1,
    const float* __restrict__ W2, const float* __restrict__ b2,
    const float* __restrict__ W3, const float* __restrict__ b3,
    const float* __restrict__ g1, const float* __restrict__ be1,
    const float* __restrict__ m1, const float* __restrict__ v1,
    const float* __restrict__ g2, const float* __restrict__ be2,
    const float* __restrict__ m2, const float* __restrict__ v2,
    float* __restrict__ out)
{
  __shared__ float lds[1200];
  __shared__ float2 spill[4096];
  __shared__ float4 ybuf[1024];
  int t = threadIdx.x;
  stage_weights(lds, t, W1,b1,W2,b2,W3,b3, g1,be1,m1,v1, g2,be2,m2,v2);

  int gid = blockIdx.x * 256 + t;
  float xpx = x[3*gid], xpy = x[3*gid+1], xpz = x[3*gid+2];
  float s[16]; int si[16];
  #pragma unroll
  for (int j = 0; j < 16; ++j) { s[j] = BIGF; si[j] = 0; }

  for (int base = 0; base < M_PTS; base += 1024) {
    int nload = M_PTS - base; if (nload > 1024) nload = 1024;
    __syncthreads();
    for (int k = t; k < nload; k += 256) {
      int i = base + k;
      ybuf[k] = make_float4(y[3*i], y[3*i+1], y[3*i+2], __int_as_float(i));
    }
    __syncthreads();
    for (int i2 = 0; i2 < nload; ++i2) {
      float4 q = ybuf[i2];
      float dx = xpx - q.x, dy = xpy - q.y, dz = xpz - q.z;
      float d = fmaf(dx, dx, fmaf(dy, dy, dz*dz));
      if (d < s[15]) topk_insert(s, si, d, __float_as_int(q.w));
    }
  }

  #pragma unroll
  for (int j = 0; j < 16; ++j) spill[j*256 + t] = make_float2(s[j], __int_as_float(si[j]));
  mlp_and_store(lds, spill, t, yat, out, gid);
}

extern "C" void kernel_launch(void* const* d_in, const int* in_sizes, int n_in,
                              void* d_out, int out_size, void* d_ws, size_t ws_size,
                              hipStream_t stream) {
  const float* x   = (const float*)d_in[0];
  const float* y   = (const float*)d_in[1];
  const float* yat = (const float*)d_in[2];
  const float* W1  = (const float*)d_in[5];
  const float* b1  = (const float*)d_in[6];
  const float* W2  = (const float*)d_in[7];
  const float* b2  = (const float*)d_in[8];
  const float* W3  = (const float*)d_in[9];
  const float* b3  = (const float*)d_in[10];
  const float* g1  = (const float*)d_in[11];
  const float* be1 = (const float*)d_in[12];
  const float* m1  = (const float*)d_in[13];
  const float* v1  = (const float*)d_in[14];
  const float* g2  = (const float*)d_in[15];
  const float* be2 = (const float*)d_in[16];
  const float* m2  = (const float*)d_in[17];
  const float* v2  = (const float*)d_in[18];
  float* out = (float*)d_out;

  // split-path ws layout (bytes):
  //   ys4    @ 0       : 320000
  //   xs4    @ 320000  : 1310720   (N float4: coords + orig idx)
  //   xorder @ 1630720 : 327680
  //   pi     @ 1958400 : 2621440   (N*16 u16, [gid][j])
  //   ycnt   @ 4579840 : 8800
  //   xcnt   @ 4588640 : 8800
  //   ystart @ 4597440 : 8800
  //   ycur   @ 4606240 : 8800
  //   xstart @ 4615040 : 8800
  //   xcur   @ 4623840 : 8800      -> end 4632640
  const size_t WS_SPLIT = 4632640;
  const size_t WS_FUSED = 700480;

  if (ws_size >= WS_SPLIT) {
    char* ws = (char*)d_ws;
    float4* ys4 = (float4*)(ws);
    float4* xs4 = (float4*)(ws + 320000);
    int* xorder = (int*)(ws + 1630720);
    unsigned short* pi = (unsigned short*)(ws + 1958400);
    int* ycnt   = (int*)(ws + 4579840);
    int* xcnt   = (int*)(ws + 4588640);
    int* ystart = (int*)(ws + 4597440);
    int* ycur   = (int*)(ws + 4606240);
    int* xstart = (int*)(ws + 4615040);
    int* xcur   = (int*)(ws + 4623840);

    hipMemsetAsync(ws + 4579840, 0, 17600, stream);   // ycnt + xcnt
    int grid_mn = (M_PTS + N_PTS + 255) / 256;
    hist_both_kernel<<<grid_mn, 256, 0, stream>>>(y, x, ycnt, xcnt);
    scan2_kernel<<<2, 1024, 0, stream>>>(ycnt, ystart, ycur, xcnt, xstart, xcur);
    scatter_both_kernel<<<grid_mn, 256, 0, stream>>>(y, x, ycur, xcur, ys4, xorder, xs4);
    // no sortcell: key-space selection is scan-order independent
    knn_cell_kernel<<<NCELLS*CHUNKS, 64, 0, stream>>>(xs4, ys4, ystart, xstart, pi);
    mlp_kernel<<<(N_PTS*16)/256, 256, 0, stream>>>(yat, xs4, y, W1,b1,W2,b2,W3,b3,
        g1,be1,m1,v1, g2,be2,m2,v2, pi, out);
  } else if (ws_size >= WS_FUSED) {
    char* ws = (char*)d_ws;
    float4* ys4 = (float4*)(ws);
    int* xorder = (int*)(ws + 320000);
    int* ycnt   = (int*)(ws + 647680);
    int* xcnt   = (int*)(ws + 656480);
    int* ystart = (int*)(ws + 665280);
    int* ycur   = (int*)(ws + 674080);
    int* xstart = (int*)(ws + 682880);
    int* xcur   = (int*)(ws + 691680);

    hipMemsetAsync(ws + 647680, 0, 17588, stream);
    int grid_mn = (M_PTS + N_PTS + 255) / 256;
    hist_both_kernel<<<grid_mn, 256, 0, stream>>>(y, x, ycnt, xcnt);
    scan2_kernel<<<2, 1024, 0, stream>>>(ycnt, ystart, ycur, xcnt, xstart, xcur);
    scatter_both_kernel<<<grid_mn, 256, 0, stream>>>(y, x, ycur, xcur, ys4, xorder, nullptr);
    sortcell_kernel<<<(NCELLS+255)/256, 256, 0, stream>>>(ys4, ystart);
    knn_mlp_fused_kernel<<<N_PTS/256, 256, 0, stream>>>(x, yat, W1,b1,W2,b2,W3,b3,
        g1,be1,m1,v1, g2,be2,m2,v2, ys4, ystart, xorder, out);
  } else {
    brute_kernel<<<N_PTS/256, 256, 0, stream>>>(x, y, yat, W1,b1,W2,b2,W3,b3,
        g1,be1,m1,v1, g2,be2,m2,v2, out);
  }
}

// Round 11
// 152.035 us; speedup vs baseline: 1.2433x; 1.2433x over previous
//
#include <hip/hip_runtime.h>

#define N_PTS 81920
#define M_PTS 20000
#define NC 13
#define NCELLS 2197
#define CELLW 0.7692307692f
#define INVCELL 1.3f
#define BIGF 3.0e38f
#define CAP_STAGE 312
#define CHUNKS 8
#define PPC 16   // points per chunk (x 4 subs = 64 lanes)
#define WPB 4    // wave-tasks per 256-thread workgroup

__device__ __forceinline__ int clampi(int v, int lo, int hi) {
  return v < lo ? lo : (v > hi ? hi : v);
}
__device__ __forceinline__ int cell_coord(float p) {
  return clampi((int)(p * INVCELL), 0, NC - 1);
}
__device__ __forceinline__ float floorpack(float d) {
  return __uint_as_float(__float_as_uint(d) & 0xFFFF8000u);
}

// ---- setup kernels ----

__global__ void hist_both_kernel(const float* __restrict__ y, const float* __restrict__ x,
                                 int* __restrict__ ycnt, int* __restrict__ xcnt) {
  int i = blockIdx.x * blockDim.x + threadIdx.x;
  if (i < M_PTS) {
    int c = (cell_coord(y[3*i+2])*NC + cell_coord(y[3*i+1]))*NC + cell_coord(y[3*i]);
    atomicAdd(&ycnt[c], 1);
  } else {
    int j = i - M_PTS;
    if (j < N_PTS) {
      int c = (cell_coord(x[3*j+2])*NC + cell_coord(x[3*j+1]))*NC + cell_coord(x[3*j]);
      atomicAdd(&xcnt[c], 1);
    }
  }
}

__global__ void scan2_kernel(const int* __restrict__ ycnt, int* __restrict__ ystart, int* __restrict__ ycur,
                             const int* __restrict__ xcnt, int* __restrict__ xstart, int* __restrict__ xcur) {
  const int* cnt = (blockIdx.x == 0) ? ycnt : xcnt;
  int* start     = (blockIdx.x == 0) ? ystart : xstart;
  int* cursor    = (blockIdx.x == 0) ? ycur : xcur;
  __shared__ int tmp[1024];
  int tid = threadIdx.x;
  int chunk = (NCELLS + 1023) >> 10;
  int base = tid * chunk;
  int sum = 0;
  for (int k = 0; k < chunk; ++k) {
    int j = base + k;
    if (j < NCELLS) sum += cnt[j];
  }
  tmp[tid] = sum;
  __syncthreads();
  for (int off = 1; off < 1024; off <<= 1) {
    int v = (tid >= off) ? tmp[tid - off] : 0;
    __syncthreads();
    tmp[tid] += v;
    __syncthreads();
  }
  int run = tmp[tid] - sum;
  for (int k = 0; k < chunk; ++k) {
    int j = base + k;
    if (j < NCELLS) { start[j] = run; cursor[j] = run; run += cnt[j]; }
  }
  if (tid == 1023) start[NCELLS] = tmp[1023];
}

__global__ void scatter_both_kernel(const float* __restrict__ y, const float* __restrict__ x,
                                    int* __restrict__ ycur, int* __restrict__ xcur,
                                    float4* __restrict__ ys4, int* __restrict__ xorder,
                                    float4* __restrict__ xs4) {
  int i = blockIdx.x * blockDim.x + threadIdx.x;
  if (i < M_PTS) {
    float px = y[3*i], py = y[3*i+1], pz = y[3*i+2];
    int c = (cell_coord(pz)*NC + cell_coord(py))*NC + cell_coord(px);
    int pos = atomicAdd(&ycur[c], 1);
    ys4[pos] = make_float4(px, py, pz, __int_as_float(i));
  } else {
    int j = i - M_PTS;
    if (j < N_PTS) {
      float px = x[3*j], py = x[3*j+1], pz = x[3*j+2];
      int c = (cell_coord(pz)*NC + cell_coord(py))*NC + cell_coord(px);
      int pos = atomicAdd(&xcur[c], 1);
      xorder[pos] = j;
      if (xs4) xs4[pos] = make_float4(px, py, pz, __int_as_float(j));
    }
  }
}

// (fused/brute fallback only) determinism: in-cell sort by original index
__global__ void sortcell_kernel(float4* __restrict__ ys4, const int* __restrict__ ystart) {
  int c = blockIdx.x * blockDim.x + threadIdx.x;
  if (c >= NCELLS) return;
  int r0 = ystart[c], r1 = ystart[c+1];
  for (int i = r0 + 1; i < r1; ++i) {
    float4 v = ys4[i];
    int key = __float_as_int(v.w);
    int j = i - 1;
    while (j >= r0 && __float_as_int(ys4[j].w) > key) { ys4[j+1] = ys4[j]; --j; }
    ys4[j+1] = v;
  }
}

// sort a bitonic 16-sequence ascending (valid only for bitonic input)
__device__ __forceinline__ void bitonic_sort16(float (&d)[16]) {
  #define CE(a,b) { float lo=fminf(d[a],d[b]); float hi=fmaxf(d[a],d[b]); d[a]=lo; d[b]=hi; }
  CE(0,8) CE(1,9) CE(2,10) CE(3,11) CE(4,12) CE(5,13) CE(6,14) CE(7,15)
  CE(0,4) CE(1,5) CE(2,6) CE(3,7) CE(8,12) CE(9,13) CE(10,14) CE(11,15)
  CE(0,2) CE(1,3) CE(4,6) CE(5,7) CE(8,10) CE(9,11) CE(12,14) CE(13,15)
  CE(0,1) CE(2,3) CE(4,5) CE(6,7) CE(8,9) CE(10,11) CE(12,13) CE(14,15)
  #undef CE
}

// branchless sorted insert into ascending 16-list; ~31 VALU ops
__device__ __forceinline__ void ins16(float (&s)[16], float k) {
  #pragma unroll
  for (int j = 15; j >= 1; --j) s[j] = fminf(fmaxf(s[j-1], k), s[j]);
  s[0] = fminf(s[0], k);
}

// ---- split path kernel A: kNN; 4 independent wave-tasks per 256-thread WG ----
// Each wave owns one (cell,chunk) task and a private 5KB LDS slice; no block
// barriers (per-wave staging + wave-local waitcnt fence). TPP=4 within the wave.
// key = (d_bits & 0xFFFF8000) | id -> exact in key space, scan-order
// independent, replay-deterministic (identical selection to R9).
__global__ void __launch_bounds__(256) knn_cell_kernel(
    const float4* __restrict__ xs4,
    const float4* __restrict__ ys4, const int* __restrict__ ystart,
    const int* __restrict__ xstart,
    unsigned short* __restrict__ pi)
{
  __shared__ float4 cand_all[WPB][CAP_STAGE];
  int wid = threadIdx.x >> 6;
  int tid = threadIdx.x & 63;           // lane within wave
  int task = blockIdx.x * WPB + wid;    // grid = NCELLS*CHUNKS/WPB blocks
  int c = task / CHUNKS, chunk = task % CHUNKS;
  int cbeg = xstart[c];
  int cend = xstart[c+1];
  int pbeg = cbeg + chunk*PPC;
  int pend = min(cend, pbeg + PPC);
  if (pbeg >= pend) return;             // wave-uniform; no barriers to violate

  float4* cand = cand_all[wid];

  int ccx = c % NC, ccy = (c / NC) % NC, ccz = c / (NC*NC);
  int x0 = ccx-1 < 0 ? 0 : ccx-1, x1 = ccx+1 > NC-1 ? NC-1 : ccx+1;
  int y0 = ccy-1 < 0 ? 0 : ccy-1, y1 = ccy+1 > NC-1 ? NC-1 : ccy+1;
  int z0 = ccz-1 < 0 ? 0 : ccz-1, z1 = ccz+1 > NC-1 ? NC-1 : ccz+1;

  // stage clamped 3x3x3 region into this wave's slice (rows contiguous in ys4)
  int off = 0, nst = 0; bool ovf = false;
  for (int gz = z0; gz <= z1; ++gz) {
    for (int gy = y0; gy <= y1; ++gy) {
      int rowbase = (gz*NC + gy)*NC;
      int r0 = ystart[rowbase + x0];
      int r1 = ystart[rowbase + x1 + 1];
      int len = r1 - r0;
      if (!ovf && off + len <= CAP_STAGE) {
        for (int k = tid; k < len; k += 64) cand[off + k] = ys4[r0 + k];
        off += len; ++nst;
      } else ovf = true;
    }
  }
  int L = off;
  // wave-local fence: all global loads landed, all LDS writes visible to wave
  asm volatile("s_waitcnt vmcnt(0) lgkmcnt(0)" ::: "memory");

  int g = tid >> 2, sub = tid & 3;
  int pidx = pbeg + g;
  bool active = pidx < pend;
  int gid = active ? pidx : (pend - 1);   // inactive groups dup last point
  float4 xq = xs4[gid];
  float xpx = xq.x, xpy = xq.y, xpz = xq.z;

  float s[16];
  #pragma unroll
  for (int j = 0; j < 16; ++j) s[j] = BIGF;

  auto packkey = [&](float4 q) -> float {
    float dx = xpx - q.x, dy = xpy - q.y, dz = xpz - q.z;
    float d = fmaf(dx, dx, fmaf(dy, dy, dz*dz));
    unsigned kb = (__float_as_uint(d) & 0xFFFF8000u) | (__float_as_uint(q.w) & 0x7FFFu);
    return __uint_as_float(kb);
  };

  // exact union top-16 across the 4 subs of this group (identical in all 4 lanes)
  auto merged16 = [&](float (&u)[16]) {
    float cb[16];
    #pragma unroll
    for (int i = 0; i < 16; ++i) cb[i] = fminf(s[i], __shfl_xor(s[15-i], 1));
    bitonic_sort16(cb);
    #pragma unroll
    for (int i = 0; i < 16; ++i) u[i] = fminf(cb[i], __shfl_xor(cb[15-i], 2));
    bitonic_sort16(u);
  };

  { // scan staged candidates: stride-4 sub partition, broadcast LDS reads
    int i = sub;
    for (; i + 4 < L; i += 8) {
      float4 q0 = cand[i], q1 = cand[i+4];
      float k0 = packkey(q0), k1 = packkey(q1);
      ins16(s, k0); ins16(s, k1);
    }
    for (; i < L; i += 4) ins16(s, packkey(cand[i]));
  }

  auto scan_row_g = [&](int xa, int xb, int rowbase) {
    int r0 = ystart[rowbase + xa];
    int r1 = ystart[rowbase + xb + 1];
    int i = r0 + sub;
    for (; i + 4 < r1; i += 8) {
      float4 q0 = ys4[i], q1 = ys4[i+4];
      float k0 = packkey(q0), k1 = packkey(q1);
      ins16(s, k0); ins16(s, k1);
    }
    for (; i < r1; i += 4) ins16(s, packkey(ys4[i]));
  };

  if (ovf) { // staged prefix only; scan remaining region rows from global (rare)
    int cnt2 = 0;
    for (int gz = z0; gz <= z1; ++gz)
      for (int gy = y0; gy <= y1; ++gy) {
        if (cnt2 >= nst) scan_row_g(x0, x1, (gz*NC + gy)*NC);
        ++cnt2;
      }
  }

  // ring expansion (exact in key space) with row/cell culling vs merged 16th
  float u[16];
  merged16(u);
  float s15m = u[15];
  int R = 1;
  while (true) {
    float b = BIGF;
    if (ccx - R >= 0)    b = fminf(b, xpx - (float)(ccx-R)*CELLW);
    if (ccx + R <= NC-2) b = fminf(b, (float)(ccx+R+1)*CELLW - xpx);
    if (ccy - R >= 0)    b = fminf(b, xpy - (float)(ccy-R)*CELLW);
    if (ccy + R <= NC-2) b = fminf(b, (float)(ccy+R+1)*CELLW - xpy);
    if (ccz - R >= 0)    b = fminf(b, xpz - (float)(ccz-R)*CELLW);
    if (ccz + R <= NC-2) b = fminf(b, (float)(ccz+R+1)*CELLW - xpz);
    b = fmaxf(b - 1e-4f, 0.0f);          // conservative vs binning rounding
    if (s15m <= floorpack(b*b) || R >= NC) break;
    ++R;
    int z0r = ccz-R < 0 ? 0 : ccz-R, z1r = ccz+R > NC-1 ? NC-1 : ccz+R;
    int y0r = ccy-R < 0 ? 0 : ccy-R, y1r = ccy+R > NC-1 ? NC-1 : ccy+R;
    int x0r = ccx-R < 0 ? 0 : ccx-R, x1r = ccx+R > NC-1 ? NC-1 : ccx+R;
    for (int gz = z0r; gz <= z1r; ++gz) {
      int dzz = gz - ccz; if (dzz < 0) dzz = -dzz;
      float gapz = (gz > ccz) ? ((float)gz*CELLW - xpz)
                 : ((gz < ccz) ? (xpz - (float)(gz+1)*CELLW) : 0.0f);
      gapz = fmaxf(gapz - 1e-4f, 0.0f);
      float gz2 = gapz * gapz;
      for (int gy = y0r; gy <= y1r; ++gy) {
        int dyy = gy - ccy; if (dyy < 0) dyy = -dyy;
        float gapy = (gy > ccy) ? ((float)gy*CELLW - xpy)
                   : ((gy < ccy) ? (xpy - (float)(gy+1)*CELLW) : 0.0f);
        gapy = fmaxf(gapy - 1e-4f, 0.0f);
        float rowd2 = fmaf(gapy, gapy, gz2);
        if (floorpack(rowd2) >= s15m) continue;   // row can't beat union 16th
        int rowbase = (gz*NC + gy)*NC;
        if (dzz == R || dyy == R) {
          scan_row_g(x0r, x1r, rowbase);
        } else {
          if (ccx - R >= 0) {
            float gapx = fmaxf(xpx - (float)(ccx-R+1)*CELLW - 1e-4f, 0.0f);
            if (floorpack(fmaf(gapx, gapx, rowd2)) < s15m)
              scan_row_g(ccx-R, ccx-R, rowbase);
          }
          if (ccx + R <= NC-1) {
            float gapx = fmaxf((float)(ccx+R)*CELLW - xpx - 1e-4f, 0.0f);
            if (floorpack(fmaf(gapx, gapx, rowd2)) < s15m)
              scan_row_g(ccx+R, ccx+R, rowbase);
          }
        }
      }
    }
    merged16(u);
    s15m = u[15];
  }

  if (active) {  // each sub writes 4 u16 ids of the sorted union (8B store)
    float v0 = u[sub*4+0], v1 = u[sub*4+1], v2 = u[sub*4+2], v3 = u[sub*4+3];
    unsigned wlo = (__float_as_uint(v0) & 0x7FFFu) | ((__float_as_uint(v1) & 0x7FFFu) << 16);
    unsigned whi = (__float_as_uint(v2) & 0x7FFFu) | ((__float_as_uint(v3) & 0x7FFFu) << 16);
    uint2 W; W.x = wlo; W.y = whi;
    ((uint2*)pi)[gid*4 + sub] = W;
  }
}

// ---- split path kernel B: MLP, one lane per (point, neighbor) ----
template<int CTRL>
__device__ __forceinline__ float ror_add(float v) {
  int r = __builtin_amdgcn_update_dpp(0, __float_as_int(v), CTRL, 0xF, 0xF, true);
  return v + __int_as_float(r);
}
__device__ __forceinline__ float red16(float v) {
  v = ror_add<0x121>(v);   // row_ror:1
  v = ror_add<0x122>(v);   // row_ror:2
  v = ror_add<0x124>(v);   // row_ror:4
  v = ror_add<0x128>(v);   // row_ror:8
  return v;                // every lane of the 16-row holds the 16-lane sum
}

__global__ void __launch_bounds__(256) mlp_kernel(
    const float* __restrict__ yat, const float4* __restrict__ xs4, const float* __restrict__ y,
    const float* __restrict__ W1, const float* __restrict__ b1,
    const float* __restrict__ W2, const float* __restrict__ b2,
    const float* __restrict__ W3, const float* __restrict__ b3,
    const float* __restrict__ g1, const float* __restrict__ be1,
    const float* __restrict__ m1, const float* __restrict__ v1,
    const float* __restrict__ g2, const float* __restrict__ be2,
    const float* __restrict__ m2, const float* __restrict__ v2,
    const unsigned short* __restrict__ pi, float* __restrict__ out)
{
  int t = threadIdx.x;
  int o = t & 15;                              // lane's neighbor slot / out channel
  int gid = (blockIdx.x * 256 + t) >> 4;       // grid = N_PTS*16 threads
  float4 xq = xs4[gid];                        // broadcast within group
  int p = __float_as_int(xq.w);

  int id = (int)pi[gid*16 + o];                // 32B per group, coalesced
  // recompute exact squared distance (selection used truncated keys)
  float dx = xq.x - y[3*id], dy = xq.y - y[3*id+1], dz = xq.z - y[3*id+2];
  float dist = fmaf(dx, dx, fmaf(dy, dy, dz*dz));
  float invd = 1.0f / dist;                    // feature = 1/(squared dist)

  const float4* a4 = (const float4*)(yat + ((size_t)id << 4));
  float4 q0 = a4[0], q1 = a4[1], q2 = a4[2], q3 = a4[3];
  float a[16];
  a[0]=q0.x; a[1]=q0.y; a[2]=q0.z; a[3]=q0.w;
  a[4]=q1.x; a[5]=q1.y; a[6]=q1.z; a[7]=q1.w;
  a[8]=q2.x; a[9]=q2.y; a[10]=q2.z; a[11]=q2.w;
  a[12]=q3.x; a[13]=q3.y; a[14]=q3.z; a[15]=q3.w;

  // layer 1 (+leaky+BN1); weight indices compile-time -> wave-uniform loads
  float h[16];
  #pragma unroll
  for (int oo = 0; oo < 16; ++oo) {
    float acc = fmaf(invd, W1[256 + oo], b1[oo]);
    #pragma unroll
    for (int i = 0; i < 16; ++i) acc = fmaf(a[i], W1[i*16 + oo], acc);
    acc = fmaxf(acc, 0.2f * acc);              // leaky_relu(0.2)
    float S = g1[oo] * rsqrtf(v1[oo] + 1e-5f);
    h[oo] = fmaf(acc - m1[oo], S, be1[oo]);    // BN1
  }

  // layer 2 (+leaky+BN2)
  float f2[16];
  #pragma unroll
  for (int oo = 0; oo < 16; ++oo) {
    float acc = b2[oo];
    #pragma unroll
    for (int i = 0; i < 16; ++i) acc = fmaf(h[i], W2[i*16 + oo], acc);
    acc = fmaxf(acc, 0.2f * acc);
    float S = g2[oo] * rsqrtf(v2[oo] + 1e-5f);
    f2[oo] = fmaf(acc - m2[oo], S, be2[oo]);
  }

  // final layer fused with cross-neighbor DPP reduction; lane owns channel o
  float acc = b3[o];
  #pragma unroll
  for (int i = 0; i < 16; ++i) acc = fmaf(red16(h[i]),  W3[i*16 + o], acc);
  #pragma unroll
  for (int i = 0; i < 16; ++i) acc = fmaf(red16(f2[i]), W3[(16 + i)*16 + o], acc);

  out[(size_t)p*16 + o] = acc;                 // 64B per group, coalesced
}

// ---- fallback 1: fused kernel (only if ws too small for split path) ----
__device__ __forceinline__ void stage_weights(float* lds, int t,
    const float* W1, const float* b1, const float* W2, const float* b2,
    const float* W3, const float* b3,
    const float* g1, const float* be1, const float* m1, const float* v1,
    const float* g2, const float* be2, const float* m2, const float* v2)
{
  for (int k = t; k < 272; k += 256) { int i = k >> 4, o = k & 15; lds[o*20 + i] = W1[k]; }
  for (int k = t; k < 256; k += 256) { int i = k >> 4, o = k & 15; lds[320 + o*16 + i] = W2[k]; }
  for (int k = t; k < 512; k += 256) { int i = k >> 4, o = k & 15; lds[576 + o*32 + i] = W3[k]; }
  if (t < 16) {
    lds[1088 + t] = b1[t];
    lds[1104 + t] = b2[t];
    lds[1120 + t] = b3[t];
    float s1 = g1[t] * rsqrtf(v1[t] + 1e-5f);
    lds[1136 + t] = s1;
    lds[1152 + t] = be1[t] - m1[t]*s1;
    float s2 = g2[t] * rsqrtf(v2[t] + 1e-5f);
    lds[1168 + t] = s2;
    lds[1184 + t] = be2[t] - m2[t]*s2;
  }
}

__device__ __forceinline__ void topk_insert(float (&s)[16], int (&si)[16], float d, int qi) {
  #pragma unroll
  for (int j = 15; j >= 1; --j) {
    bool c1 = d < s[j-1];
    bool c2 = d < s[j];
    float ns = c1 ? s[j-1] : (c2 ? d : s[j]);
    int  ni = c1 ? si[j-1] : (c2 ? qi : si[j]);
    s[j] = ns; si[j] = ni;
  }
  if (d < s[0]) { si[0] = qi; s[0] = d; }
}

__device__ __forceinline__ void mlp_and_store(const float* lds, const float2* spill, int t,
    const float* __restrict__ yat, float* __restrict__ out, int p)
{
  const float* W1t = lds;
  const float* W2t = lds + 320;
  const float* W3t = lds + 576;
  const float* sb1 = lds + 1088;
  const float* sb2 = lds + 1104;
  const float* sb3 = lds + 1120;
  const float* S1 = lds + 1136;
  const float* T1 = lds + 1152;
  const float* S2 = lds + 1168;
  const float* T2 = lds + 1184;

  float fx1[16], fx2[16];
  #pragma unroll
  for (int o = 0; o < 16; ++o) { fx1[o] = 0.0f; fx2[o] = 0.0f; }

  #pragma unroll 1
  for (int j = 0; j < 16; ++j) {
    float2 sv = spill[j*256 + t];
    float invd = 1.0f / sv.x;
    int id = __float_as_int(sv.y);
    const float4* a4 = (const float4*)(yat + ((size_t)id << 4));
    float4 q0 = a4[0], q1 = a4[1], q2 = a4[2], q3 = a4[3];
    float a[16];
    a[0]=q0.x; a[1]=q0.y; a[2]=q0.z; a[3]=q0.w;
    a[4]=q1.x; a[5]=q1.y; a[6]=q1.z; a[7]=q1.w;
    a[8]=q2.x; a[9]=q2.y; a[10]=q2.z; a[11]=q2.w;
    a[12]=q3.x; a[13]=q3.y; a[14]=q3.z; a[15]=q3.w;
    float h[16];
    #pragma unroll
    for (int o = 0; o < 16; ++o) {
      float acc = fmaf(invd, W1t[o*20 + 16], sb1[o]);
      #pragma unroll
      for (int i = 0; i < 16; ++i) acc = fmaf(a[i], W1t[o*20 + i], acc);
      acc = fmaxf(acc, 0.2f * acc);
      float hv = fmaf(acc, S1[o], T1[o]);
      h[o] = hv;
      fx1[o] += hv;
    }
    #pragma unroll
    for (int o = 0; o < 16; ++o) {
      float acc = sb2[o];
      #pragma unroll
      for (int i = 0; i < 16; ++i) acc = fmaf(h[i], W2t[o*16 + i], acc);
      acc = fmaxf(acc, 0.2f * acc);
      fx2[o] += fmaf(acc, S2[o], T2[o]);
    }
  }

  float res[16];
  #pragma unroll
  for (int o = 0; o < 16; ++o) {
    float acc = sb3[o];
    #pragma unroll
    for (int i = 0; i < 16; ++i) acc = fmaf(fx1[i], W3t[o*32 + i], acc);
    #pragma unroll
    for (int i = 0; i < 16; ++i) acc = fmaf(fx2[i], W3t[o*32 + 16 + i], acc);
    res[o] = acc;
  }
  float* op = out + ((size_t)p << 4);
  float4 r;
  r.x=res[0]; r.y=res[1]; r.z=res[2]; r.w=res[3];   ((float4*)op)[0] = r;
  r.x=res[4]; r.y=res[5]; r.z=res[6]; r.w=res[7];   ((float4*)op)[1] = r;
  r.x=res[8]; r.y=res[9]; r.z=res[10]; r.w=res[11]; ((float4*)op)[2] = r;
  r.x=res[12]; r.y=res[13]; r.z=res[14]; r.w=res[15];((float4*)op)[3] = r;
}

__global__ void __launch_bounds__(256) knn_mlp_fused_kernel(
    const float* __restrict__ x, const float* __restrict__ yat,
    const float* __restrict__ W1, const float* __restrict__ b1,
    const float* __restrict__ W2, const float* __restrict__ b2,
    const float* __restrict__ W3, const float* __restrict__ b3,
    const float* __restrict__ g1, const float* __restrict__ be1,
    const float* __restrict__ m1, const float* __restrict__ v1,
    const float* __restrict__ g2, const float* __restrict__ be2,
    const float* __restrict__ m2, const float* __restrict__ v2,
    const float4* __restrict__ ys4, const int* __restrict__ ystart,
    const int* __restrict__ xorder, float* __restrict__ out)
{
  __shared__ float lds[1200];
  __shared__ float2 spill[4096];
  int t = threadIdx.x;
  stage_weights(lds, t, W1,b1,W2,b2,W3,b3, g1,be1,m1,v1, g2,be2,m2,v2);
  __syncthreads();

  int gid = blockIdx.x * 256 + t;
  int p = xorder[gid];
  float xpx = x[3*p], xpy = x[3*p+1], xpz = x[3*p+2];
  int cx = cell_coord(xpx), cy = cell_coord(xpy), cz = cell_coord(xpz);

  float s[16]; int si[16];
  #pragma unroll
  for (int j = 0; j < 16; ++j) { s[j] = BIGF; si[j] = 0; }

  auto scan_row = [&](int gz, int gy, int xa, int xb) {
    int rowbase = (gz*NC + gy)*NC;
    int r0 = ystart[rowbase + xa];
    int r1 = ystart[rowbase + xb + 1];
    for (int i = r0; i < r1; ++i) {
      float4 q = ys4[i];
      float dx = xpx - q.x, dy = xpy - q.y, dz = xpz - q.z;
      float d = fmaf(dx, dx, fmaf(dy, dy, dz*dz));
      if (d < s[15]) topk_insert(s, si, d, __float_as_int(q.w));
    }
  };

  {
    int z0 = cz-1 < 0 ? 0 : cz-1, z1 = cz+1 > NC-1 ? NC-1 : cz+1;
    int y0 = cy-1 < 0 ? 0 : cy-1, y1 = cy+1 > NC-1 ? NC-1 : cy+1;
    int x0 = cx-1 < 0 ? 0 : cx-1, x1 = cx+1 > NC-1 ? NC-1 : cx+1;
    for (int gz = z0; gz <= z1; ++gz)
      for (int gy = y0; gy <= y1; ++gy)
        scan_row(gz, gy, x0, x1);
  }

  int R = 1;
  while (true) {
    float b = BIGF;
    if (cx - R >= 0)    b = fminf(b, xpx - (float)(cx-R)*CELLW);
    if (cx + R <= NC-2) b = fminf(b, (float)(cx+R+1)*CELLW - xpx);
    if (cy - R >= 0)    b = fminf(b, xpy - (float)(cy-R)*CELLW);
    if (cy + R <= NC-2) b = fminf(b, (float)(cy+R+1)*CELLW - xpy);
    if (cz - R >= 0)    b = fminf(b, xpz - (float)(cz-R)*CELLW);
    if (cz + R <= NC-2) b = fminf(b, (float)(cz+R+1)*CELLW - xpz);
    b = fmaxf(b - 1e-4f, 0.0f);
    if (s[15] <= b*b || R >= NC) break;
    ++R;
    int z0 = cz-R < 0 ? 0 : cz-R, z1 = cz+R > NC-1 ? NC-1 : cz+R;
    int y0 = cy-R < 0 ? 0 : cy-R, y1 = cy+R > NC-1 ? NC-1 : cy+R;
    int x0 = cx-R < 0 ? 0 : cx-R, x1 = cx+R > NC-1 ? NC-1 : cx+R;
    for (int gz = z0; gz <= z1; ++gz) {
      int dzz = gz - cz; if (dzz < 0) dzz = -dzz;
      for (int gy = y0; gy <= y1; ++gy) {
        int dyy = gy - cy; if (dyy < 0) dyy = -dyy;
        if (dzz == R || dyy == R) {
          scan_row(gz, gy, x0, x1);
        } else {
          if (cx - R >= 0)    scan_row(gz, gy, cx-R, cx-R);
          if (cx + R <= NC-1) scan_row(gz, gy, cx+R, cx+R);
        }
      }
    }
  }

  #pragma unroll
  for (int j = 0; j < 16; ++j) spill[j*256 + t] = make_float2(s[j], __int_as_float(si[j]));
  mlp_and_store(lds, spill, t, yat, out, p);
}

// ---- fallback 2: brute force (no workspace needed) ----
__global__ void __launch_bounds__(256) brute_kernel(
    const float* __restrict__ x, const float* __restrict__ y, const float* __restrict__ yat,
    const float* __restrict__ W1, const float* __restrict__ b1,
    const float* __restrict__ W2, const float* __restrict__ b2,
    const float* __restrict__ W3, const float* __restrict__ b3,
    const float* __restrict__ g1, const float* __restrict__ be1,
    const float* __restrict__ m1, const float* __restrict__ v1,
    const float* __restrict__ g2, const float* __restrict__ be2,
    const float* __restrict__ m2, const float* __restrict__ v2,
    float* __restrict__ out)
{
  __shared__ float lds[1200];
  __shared__ float2 spill[4096];
  __shared__ float4 ybuf[1024];
  int t = threadIdx.x;
  stage_weights(lds, t, W1,b1,W2,b2,W3,b3, g1,be1,m1,v1, g2,be2,m2,v2);

  int gid = blockIdx.x * 256 + t;
  float xpx = x[3*gid], xpy = x[3*gid+1], xpz = x[3*gid+2];
  float s[16]; int si[16];
  #pragma unroll
  for (int j = 0; j < 16; ++j) { s[j] = BIGF; si[j] = 0; }

  for (int base = 0; base < M_PTS; base += 1024) {
    int nload = M_PTS - base; if (nload > 1024) nload = 1024;
    __syncthreads();
    for (int k = t; k < nload; k += 256) {
      int i = base + k;
      ybuf[k] = make_float4(y[3*i], y[3*i+1], y[3*i+2], __int_as_float(i));
    }
    __syncthreads();
    for (int i2 = 0; i2 < nload; ++i2) {
      float4 q = ybuf[i2];
      float dx = xpx - q.x, dy = xpy - q.y, dz = xpz - q.z;
      float d = fmaf(dx, dx, fmaf(dy, dy, dz*dz));
      if (d < s[15]) topk_insert(s, si, d, __float_as_int(q.w));
    }
  }

  #pragma unroll
  for (int j = 0; j < 16; ++j) spill[j*256 + t] = make_float2(s[j], __int_as_float(si[j]));
  mlp_and_store(lds, spill, t, yat, out, gid);
}

extern "C" void kernel_launch(void* const* d_in, const int* in_sizes, int n_in,
                              void* d_out, int out_size, void* d_ws, size_t ws_size,
                              hipStream_t stream) {
  const float* x   = (const float*)d_in[0];
  const float* y   = (const float*)d_in[1];
  const float* yat = (const float*)d_in[2];
  const float* W1  = (const float*)d_in[5];
  const float* b1  = (const float*)d_in[6];
  const float* W2  = (const float*)d_in[7];
  const float* b2  = (const float*)d_in[8];
  const float* W3  = (const float*)d_in[9];
  const float* b3  = (const float*)d_in[10];
  const float* g1  = (const float*)d_in[11];
  const float* be1 = (const float*)d_in[12];
  const float* m1  = (const float*)d_in[13];
  const float* v1  = (const float*)d_in[14];
  const float* g2  = (const float*)d_in[15];
  const float* be2 = (const float*)d_in[16];
  const float* m2  = (const float*)d_in[17];
  const float* v2  = (const float*)d_in[18];
  float* out = (float*)d_out;

  // split-path ws layout (bytes):
  //   ys4    @ 0       : 320000
  //   xs4    @ 320000  : 1310720   (N float4: coords + orig idx)
  //   xorder @ 1630720 : 327680
  //   pi     @ 1958400 : 2621440   (N*16 u16, [gid][j])
  //   ycnt   @ 4579840 : 8800
  //   xcnt   @ 4588640 : 8800
  //   ystart @ 4597440 : 8800
  //   ycur   @ 4606240 : 8800
  //   xstart @ 4615040 : 8800
  //   xcur   @ 4623840 : 8800      -> end 4632640
  const size_t WS_SPLIT = 4632640;
  const size_t WS_FUSED = 700480;

  if (ws_size >= WS_SPLIT) {
    char* ws = (char*)d_ws;
    float4* ys4 = (float4*)(ws);
    float4* xs4 = (float4*)(ws + 320000);
    int* xorder = (int*)(ws + 1630720);
    unsigned short* pi = (unsigned short*)(ws + 1958400);
    int* ycnt   = (int*)(ws + 4579840);
    int* xcnt   = (int*)(ws + 4588640);
    int* ystart = (int*)(ws + 4597440);
    int* ycur   = (int*)(ws + 4606240);
    int* xstart = (int*)(ws + 4615040);
    int* xcur   = (int*)(ws + 4623840);

    hipMemsetAsync(ws + 4579840, 0, 17600, stream);   // ycnt + xcnt
    int grid_mn = (M_PTS + N_PTS + 255) / 256;
    hist_both_kernel<<<grid_mn, 256, 0, stream>>>(y, x, ycnt, xcnt);
    scan2_kernel<<<2, 1024, 0, stream>>>(ycnt, ystart, ycur, xcnt, xstart, xcur);
    scatter_both_kernel<<<grid_mn, 256, 0, stream>>>(y, x, ycur, xcur, ys4, xorder, xs4);
    // no sortcell: key-space selection is scan-order independent
    knn_cell_kernel<<<(NCELLS*CHUNKS)/WPB, 256, 0, stream>>>(xs4, ys4, ystart, xstart, pi);
    mlp_kernel<<<(N_PTS*16)/256, 256, 0, stream>>>(yat, xs4, y, W1,b1,W2,b2,W3,b3,
        g1,be1,m1,v1, g2,be2,m2,v2, pi, out);
  } else if (ws_size >= WS_FUSED) {
    char* ws = (char*)d_ws;
    float4* ys4 = (float4*)(ws);
    int* xorder = (int*)(ws + 320000);
    int* ycnt   = (int*)(ws + 647680);
    int* xcnt   = (int*)(ws + 656480);
    int* ystart = (int*)(ws + 665280);
    int* ycur   = (int*)(ws + 674080);
    int* xstart = (int*)(ws + 682880);
    int* xcur   = (int*)(ws + 691680);

    hipMemsetAsync(ws + 647680, 0, 17588, stream);
    int grid_mn = (M_PTS + N_PTS + 255) / 256;
    hist_both_kernel<<<grid_mn, 256, 0, stream>>>(y, x, ycnt, xcnt);
    scan2_kernel<<<2, 1024, 0, stream>>>(ycnt, ystart, ycur, xcnt, xstart, xcur);
    scatter_both_kernel<<<grid_mn, 256, 0, stream>>>(y, x, ycur, xcur, ys4, xorder, nullptr);
    sortcell_kernel<<<(NCELLS+255)/256, 256, 0, stream>>>(ys4, ystart);
    knn_mlp_fused_kernel<<<N_PTS/256, 256, 0, stream>>>(x, yat, W1,b1,W2,b2,W3,b3,
        g1,be1,m1,v1, g2,be2,m2,v2, ys4, ystart, xorder, out);
  } else {
    brute_kernel<<<N_PTS/256, 256, 0, stream>>>(x, y, yat, W1,b1,W2,b2,W3,b3,
        g1,be1,m1,v1, g2,be2,m2,v2, out);
  }
}

// Round 12
// 122.336 us; speedup vs baseline: 1.5451x; 1.2428x over previous
//
#include <hip/hip_runtime.h>

#define N_PTS 81920
#define M_PTS 20000
#define NC 13
#define NCELLS 2197
#define CELLW 0.7692307692f
#define INVCELL 1.3f
#define BIGF 3.0e38f
#define CAP_STAGE 312
#define PPC 16   // points per task (x 4 subs = 64 lanes)
#define WPB 4    // wave-tasks per 256-thread workgroup
#define MAX_TASKS 7320   // >= NCELLS + N_PTS/PPC

__device__ __forceinline__ int clampi(int v, int lo, int hi) {
  return v < lo ? lo : (v > hi ? hi : v);
}
__device__ __forceinline__ int cell_coord(float p) {
  return clampi((int)(p * INVCELL), 0, NC - 1);
}
__device__ __forceinline__ float floorpack(float d) {
  return __uint_as_float(__float_as_uint(d) & 0xFFFF8000u);
}

// ---- setup kernels ----

__global__ void hist_both_kernel(const float* __restrict__ y, const float* __restrict__ x,
                                 int* __restrict__ ycnt, int* __restrict__ xcnt) {
  int i = blockIdx.x * blockDim.x + threadIdx.x;
  if (i < M_PTS) {
    int c = (cell_coord(y[3*i+2])*NC + cell_coord(y[3*i+1]))*NC + cell_coord(y[3*i]);
    atomicAdd(&ycnt[c], 1);
  } else {
    int j = i - M_PTS;
    if (j < N_PTS) {
      int c = (cell_coord(x[3*j+2])*NC + cell_coord(x[3*j+1]))*NC + cell_coord(x[3*j]);
      atomicAdd(&xcnt[c], 1);
    }
  }
}

__global__ void scan2_kernel(const int* __restrict__ ycnt, int* __restrict__ ystart, int* __restrict__ ycur,
                             const int* __restrict__ xcnt, int* __restrict__ xstart, int* __restrict__ xcur) {
  const int* cnt = (blockIdx.x == 0) ? ycnt : xcnt;
  int* start     = (blockIdx.x == 0) ? ystart : xstart;
  int* cursor    = (blockIdx.x == 0) ? ycur : xcur;
  __shared__ int tmp[1024];
  int tid = threadIdx.x;
  int chunk = (NCELLS + 1023) >> 10;
  int base = tid * chunk;
  int sum = 0;
  for (int k = 0; k < chunk; ++k) {
    int j = base + k;
    if (j < NCELLS) sum += cnt[j];
  }
  tmp[tid] = sum;
  __syncthreads();
  for (int off = 1; off < 1024; off <<= 1) {
    int v = (tid >= off) ? tmp[tid - off] : 0;
    __syncthreads();
    tmp[tid] += v;
    __syncthreads();
  }
  int run = tmp[tid] - sum;
  for (int k = 0; k < chunk; ++k) {
    int j = base + k;
    if (j < NCELLS) { start[j] = run; cursor[j] = run; run += cnt[j]; }
  }
  if (tid == 1023) start[NCELLS] = tmp[1023];
}

__global__ void scatter_both_kernel(const float* __restrict__ y, const float* __restrict__ x,
                                    int* __restrict__ ycur, int* __restrict__ xcur,
                                    float4* __restrict__ ys4, int* __restrict__ xorder,
                                    float4* __restrict__ xs4) {
  int i = blockIdx.x * blockDim.x + threadIdx.x;
  if (i < M_PTS) {
    float px = y[3*i], py = y[3*i+1], pz = y[3*i+2];
    int c = (cell_coord(pz)*NC + cell_coord(py))*NC + cell_coord(px);
    int pos = atomicAdd(&ycur[c], 1);
    ys4[pos] = make_float4(px, py, pz, __int_as_float(i));
  } else {
    int j = i - M_PTS;
    if (j < N_PTS) {
      float px = x[3*j], py = x[3*j+1], pz = x[3*j+2];
      int c = (cell_coord(pz)*NC + cell_coord(py))*NC + cell_coord(px);
      int pos = atomicAdd(&xcur[c], 1);
      xorder[pos] = j;
      if (xs4) xs4[pos] = make_float4(px, py, pz, __int_as_float(j));
    }
  }
}

// dense task list: one entry per non-empty (cell, chunk). Order nondeterministic
// (atomic), but per-point output is task-order independent -> replay-safe.
__global__ void build_tasks_kernel(const int* __restrict__ xstart,
                                   int* __restrict__ tasks, int* __restrict__ ntasks) {
  int c = blockIdx.x * blockDim.x + threadIdx.x;
  if (c >= NCELLS) return;
  int cnt = xstart[c+1] - xstart[c];
  int nch = (cnt + PPC - 1) / PPC;
  if (nch > 0) {
    int pos = atomicAdd(ntasks, nch);
    for (int k = 0; k < nch; ++k) tasks[pos + k] = (k << 12) | c;   // c < 4096
  }
}

// (fused/brute fallback only) determinism: in-cell sort by original index
__global__ void sortcell_kernel(float4* __restrict__ ys4, const int* __restrict__ ystart) {
  int c = blockIdx.x * blockDim.x + threadIdx.x;
  if (c >= NCELLS) return;
  int r0 = ystart[c], r1 = ystart[c+1];
  for (int i = r0 + 1; i < r1; ++i) {
    float4 v = ys4[i];
    int key = __float_as_int(v.w);
    int j = i - 1;
    while (j >= r0 && __float_as_int(ys4[j].w) > key) { ys4[j+1] = ys4[j]; --j; }
    ys4[j+1] = v;
  }
}

// sort a bitonic 16-sequence ascending (valid only for bitonic input)
__device__ __forceinline__ void bitonic_sort16(float (&d)[16]) {
  #define CE(a,b) { float lo=fminf(d[a],d[b]); float hi=fmaxf(d[a],d[b]); d[a]=lo; d[b]=hi; }
  CE(0,8) CE(1,9) CE(2,10) CE(3,11) CE(4,12) CE(5,13) CE(6,14) CE(7,15)
  CE(0,4) CE(1,5) CE(2,6) CE(3,7) CE(8,12) CE(9,13) CE(10,14) CE(11,15)
  CE(0,2) CE(1,3) CE(4,6) CE(5,7) CE(8,10) CE(9,11) CE(12,14) CE(13,15)
  CE(0,1) CE(2,3) CE(4,5) CE(6,7) CE(8,9) CE(10,11) CE(12,13) CE(14,15)
  #undef CE
}

// branchless sorted insert into ascending 16-list; ~31 VALU ops
__device__ __forceinline__ void ins16(float (&s)[16], float k) {
  #pragma unroll
  for (int j = 15; j >= 1; --j) s[j] = fminf(fmaxf(s[j-1], k), s[j]);
  s[0] = fminf(s[0], k);
}

// ---- split path kernel A: kNN; dense task list, 4 wave-tasks per WG ----
// Each wave owns one (cell,chunk) task and a private 5KB LDS slice; no block
// barriers (per-wave staging + wave-local waitcnt fence). TPP=4 within the wave.
// key = (d_bits & 0xFFFF8000) | id -> exact in key space, scan-order
// independent, replay-deterministic (identical selection to R9/R11).
__global__ void __launch_bounds__(256) knn_cell_kernel(
    const float4* __restrict__ xs4,
    const float4* __restrict__ ys4, const int* __restrict__ ystart,
    const int* __restrict__ xstart,
    const int* __restrict__ tasks, const int* __restrict__ ntasks,
    unsigned short* __restrict__ pi)
{
  __shared__ float4 cand_all[WPB][CAP_STAGE];
  int wid = threadIdx.x >> 6;
  int tid = threadIdx.x & 63;           // lane within wave
  int ti = blockIdx.x * WPB + wid;      // fixed grid = MAX_TASKS/WPB blocks
  if (ti >= ntasks[0]) return;          // wave-uniform; no barriers to violate
  int task = tasks[ti];
  int c = task & 4095, chunk = task >> 12;
  int cbeg = xstart[c];
  int cend = xstart[c+1];
  int pbeg = cbeg + chunk*PPC;
  int pend = min(cend, pbeg + PPC);

  float4* cand = cand_all[wid];

  int ccx = c % NC, ccy = (c / NC) % NC, ccz = c / (NC*NC);
  int x0 = ccx-1 < 0 ? 0 : ccx-1, x1 = ccx+1 > NC-1 ? NC-1 : ccx+1;
  int y0 = ccy-1 < 0 ? 0 : ccy-1, y1 = ccy+1 > NC-1 ? NC-1 : ccy+1;
  int z0 = ccz-1 < 0 ? 0 : ccz-1, z1 = ccz+1 > NC-1 ? NC-1 : ccz+1;

  // stage clamped 3x3x3 region into this wave's slice (rows contiguous in ys4)
  int off = 0, nst = 0; bool ovf = false;
  for (int gz = z0; gz <= z1; ++gz) {
    for (int gy = y0; gy <= y1; ++gy) {
      int rowbase = (gz*NC + gy)*NC;
      int r0 = ystart[rowbase + x0];
      int r1 = ystart[rowbase + x1 + 1];
      int len = r1 - r0;
      if (!ovf && off + len <= CAP_STAGE) {
        for (int k = tid; k < len; k += 64) cand[off + k] = ys4[r0 + k];
        off += len; ++nst;
      } else ovf = true;
    }
  }
  int L = off;
  // wave-local fence: all global loads landed, all LDS writes visible to wave
  asm volatile("s_waitcnt vmcnt(0) lgkmcnt(0)" ::: "memory");

  int g = tid >> 2, sub = tid & 3;
  int pidx = pbeg + g;
  bool active = pidx < pend;
  int gid = active ? pidx : (pend - 1);   // inactive groups dup last point
  float4 xq = xs4[gid];
  float xpx = xq.x, xpy = xq.y, xpz = xq.z;

  float s[16];
  #pragma unroll
  for (int j = 0; j < 16; ++j) s[j] = BIGF;

  auto packkey = [&](float4 q) -> float {
    float dx = xpx - q.x, dy = xpy - q.y, dz = xpz - q.z;
    float d = fmaf(dx, dx, fmaf(dy, dy, dz*dz));
    unsigned kb = (__float_as_uint(d) & 0xFFFF8000u) | (__float_as_uint(q.w) & 0x7FFFu);
    return __uint_as_float(kb);
  };

  // exact union top-16 across the 4 subs of this group (identical in all 4 lanes)
  auto merged16 = [&](float (&u)[16]) {
    float cb[16];
    #pragma unroll
    for (int i = 0; i < 16; ++i) cb[i] = fminf(s[i], __shfl_xor(s[15-i], 1));
    bitonic_sort16(cb);
    #pragma unroll
    for (int i = 0; i < 16; ++i) u[i] = fminf(cb[i], __shfl_xor(cb[15-i], 2));
    bitonic_sort16(u);
  };

  { // scan staged candidates: stride-4 sub partition, broadcast LDS reads
    int i = sub;
    for (; i + 4 < L; i += 8) {
      float4 q0 = cand[i], q1 = cand[i+4];
      float k0 = packkey(q0), k1 = packkey(q1);
      ins16(s, k0); ins16(s, k1);
    }
    for (; i < L; i += 4) ins16(s, packkey(cand[i]));
  }

  auto scan_row_g = [&](int xa, int xb, int rowbase) {
    int r0 = ystart[rowbase + xa];
    int r1 = ystart[rowbase + xb + 1];
    int i = r0 + sub;
    for (; i + 4 < r1; i += 8) {
      float4 q0 = ys4[i], q1 = ys4[i+4];
      float k0 = packkey(q0), k1 = packkey(q1);
      ins16(s, k0); ins16(s, k1);
    }
    for (; i < r1; i += 4) ins16(s, packkey(ys4[i]));
  };

  if (ovf) { // staged prefix only; scan remaining region rows from global (rare)
    int cnt2 = 0;
    for (int gz = z0; gz <= z1; ++gz)
      for (int gy = y0; gy <= y1; ++gy) {
        if (cnt2 >= nst) scan_row_g(x0, x1, (gz*NC + gy)*NC);
        ++cnt2;
      }
  }

  // ring expansion (exact in key space) with row/cell culling vs merged 16th
  float u[16];
  merged16(u);
  float s15m = u[15];
  int R = 1;
  while (true) {
    float b = BIGF;
    if (ccx - R >= 0)    b = fminf(b, xpx - (float)(ccx-R)*CELLW);
    if (ccx + R <= NC-2) b = fminf(b, (float)(ccx+R+1)*CELLW - xpx);
    if (ccy - R >= 0)    b = fminf(b, xpy - (float)(ccy-R)*CELLW);
    if (ccy + R <= NC-2) b = fminf(b, (float)(ccy+R+1)*CELLW - xpy);
    if (ccz - R >= 0)    b = fminf(b, xpz - (float)(ccz-R)*CELLW);
    if (ccz + R <= NC-2) b = fminf(b, (float)(ccz+R+1)*CELLW - xpz);
    b = fmaxf(b - 1e-4f, 0.0f);          // conservative vs binning rounding
    if (s15m <= floorpack(b*b) || R >= NC) break;
    ++R;
    int z0r = ccz-R < 0 ? 0 : ccz-R, z1r = ccz+R > NC-1 ? NC-1 : ccz+R;
    int y0r = ccy-R < 0 ? 0 : ccy-R, y1r = ccy+R > NC-1 ? NC-1 : ccy+R;
    int x0r = ccx-R < 0 ? 0 : ccx-R, x1r = ccx+R > NC-1 ? NC-1 : ccx+R;
    for (int gz = z0r; gz <= z1r; ++gz) {
      int dzz = gz - ccz; if (dzz < 0) dzz = -dzz;
      float gapz = (gz > ccz) ? ((float)gz*CELLW - xpz)
                 : ((gz < ccz) ? (xpz - (float)(gz+1)*CELLW) : 0.0f);
      gapz = fmaxf(gapz - 1e-4f, 0.0f);
      float gz2 = gapz * gapz;
      for (int gy = y0r; gy <= y1r; ++gy) {
        int dyy = gy - ccy; if (dyy < 0) dyy = -dyy;
        float gapy = (gy > ccy) ? ((float)gy*CELLW - xpy)
                   : ((gy < ccy) ? (xpy - (float)(gy+1)*CELLW) : 0.0f);
        gapy = fmaxf(gapy - 1e-4f, 0.0f);
        float rowd2 = fmaf(gapy, gapy, gz2);
        if (floorpack(rowd2) >= s15m) continue;   // row can't beat union 16th
        int rowbase = (gz*NC + gy)*NC;
        if (dzz == R || dyy == R) {
          scan_row_g(x0r, x1r, rowbase);
        } else {
          if (ccx - R >= 0) {
            float gapx = fmaxf(xpx - (float)(ccx-R+1)*CELLW - 1e-4f, 0.0f);
            if (floorpack(fmaf(gapx, gapx, rowd2)) < s15m)
              scan_row_g(ccx-R, ccx-R, rowbase);
          }
          if (ccx + R <= NC-1) {
            float gapx = fmaxf((float)(ccx+R)*CELLW - xpx - 1e-4f, 0.0f);
            if (floorpack(fmaf(gapx, gapx, rowd2)) < s15m)
              scan_row_g(ccx+R, ccx+R, rowbase);
          }
        }
      }
    }
    merged16(u);
    s15m = u[15];
  }

  if (active) {  // each sub writes 4 u16 ids of the sorted union (8B store)
    float v0 = u[sub*4+0], v1 = u[sub*4+1], v2 = u[sub*4+2], v3 = u[sub*4+3];
    unsigned wlo = (__float_as_uint(v0) & 0x7FFFu) | ((__float_as_uint(v1) & 0x7FFFu) << 16);
    unsigned whi = (__float_as_uint(v2) & 0x7FFFu) | ((__float_as_uint(v3) & 0x7FFFu) << 16);
    uint2 W; W.x = wlo; W.y = whi;
    ((uint2*)pi)[gid*4 + sub] = W;
  }
}

// ---- split path kernel B: MLP, one lane per (point, neighbor) ----
template<int CTRL>
__device__ __forceinline__ float ror_add(float v) {
  int r = __builtin_amdgcn_update_dpp(0, __float_as_int(v), CTRL, 0xF, 0xF, true);
  return v + __int_as_float(r);
}
__device__ __forceinline__ float red16(float v) {
  v = ror_add<0x121>(v);   // row_ror:1
  v = ror_add<0x122>(v);   // row_ror:2
  v = ror_add<0x124>(v);   // row_ror:4
  v = ror_add<0x128>(v);   // row_ror:8
  return v;                // every lane of the 16-row holds the 16-lane sum
}

__global__ void __launch_bounds__(256) mlp_kernel(
    const float* __restrict__ yat, const float4* __restrict__ xs4, const float* __restrict__ y,
    const float* __restrict__ W1, const float* __restrict__ b1,
    const float* __restrict__ W2, const float* __restrict__ b2,
    const float* __restrict__ W3, const float* __restrict__ b3,
    const float* __restrict__ g1, const float* __restrict__ be1,
    const float* __restrict__ m1, const float* __restrict__ v1,
    const float* __restrict__ g2, const float* __restrict__ be2,
    const float* __restrict__ m2, const float* __restrict__ v2,
    const unsigned short* __restrict__ pi, float* __restrict__ out)
{
  int t = threadIdx.x;
  int o = t & 15;                              // lane's neighbor slot / out channel
  int gid = (blockIdx.x * 256 + t) >> 4;       // grid = N_PTS*16 threads
  float4 xq = xs4[gid];                        // broadcast within group
  int p = __float_as_int(xq.w);

  int id = (int)pi[gid*16 + o];                // 32B per group, coalesced
  // recompute exact squared distance (selection used truncated keys)
  float dx = xq.x - y[3*id], dy = xq.y - y[3*id+1], dz = xq.z - y[3*id+2];
  float dist = fmaf(dx, dx, fmaf(dy, dy, dz*dz));
  float invd = 1.0f / dist;                    // feature = 1/(squared dist)

  const float4* a4 = (const float4*)(yat + ((size_t)id << 4));
  float4 q0 = a4[0], q1 = a4[1], q2 = a4[2], q3 = a4[3];
  float a[16];
  a[0]=q0.x; a[1]=q0.y; a[2]=q0.z; a[3]=q0.w;
  a[4]=q1.x; a[5]=q1.y; a[6]=q1.z; a[7]=q1.w;
  a[8]=q2.x; a[9]=q2.y; a[10]=q2.z; a[11]=q2.w;
  a[12]=q3.x; a[13]=q3.y; a[14]=q3.z; a[15]=q3.w;

  // layer 1 (+leaky+BN1); weight indices compile-time -> wave-uniform loads
  float h[16];
  #pragma unroll
  for (int oo = 0; oo < 16; ++oo) {
    float acc = fmaf(invd, W1[256 + oo], b1[oo]);
    #pragma unroll
    for (int i = 0; i < 16; ++i) acc = fmaf(a[i], W1[i*16 + oo], acc);
    acc = fmaxf(acc, 0.2f * acc);              // leaky_relu(0.2)
    float S = g1[oo] * rsqrtf(v1[oo] + 1e-5f);
    h[oo] = fmaf(acc - m1[oo], S, be1[oo]);    // BN1
  }

  // layer 2 (+leaky+BN2)
  float f2[16];
  #pragma unroll
  for (int oo = 0; oo < 16; ++oo) {
    float acc = b2[oo];
    #pragma unroll
    for (int i = 0; i < 16; ++i) acc = fmaf(h[i], W2[i*16 + oo], acc);
    acc = fmaxf(acc, 0.2f * acc);
    float S = g2[oo] * rsqrtf(v2[oo] + 1e-5f);
    f2[oo] = fmaf(acc - m2[oo], S, be2[oo]);
  }

  // final layer fused with cross-neighbor DPP reduction; lane owns channel o
  float acc = b3[o];
  #pragma unroll
  for (int i = 0; i < 16; ++i) acc = fmaf(red16(h[i]),  W3[i*16 + o], acc);
  #pragma unroll
  for (int i = 0; i < 16; ++i) acc = fmaf(red16(f2[i]), W3[(16 + i)*16 + o], acc);

  out[(size_t)p*16 + o] = acc;                 // 64B per group, coalesced
}

// ---- fallback 1: fused kernel (only if ws too small for split path) ----
__device__ __forceinline__ void stage_weights(float* lds, int t,
    const float* W1, const float* b1, const float* W2, const float* b2,
    const float* W3, const float* b3,
    const float* g1, const float* be1, const float* m1, const float* v1,
    const float* g2, const float* be2, const float* m2, const float* v2)
{
  for (int k = t; k < 272; k += 256) { int i = k >> 4, o = k & 15; lds[o*20 + i] = W1[k]; }
  for (int k = t; k < 256; k += 256) { int i = k >> 4, o = k & 15; lds[320 + o*16 + i] = W2[k]; }
  for (int k = t; k < 512; k += 256) { int i = k >> 4, o = k & 15; lds[576 + o*32 + i] = W3[k]; }
  if (t < 16) {
    lds[1088 + t] = b1[t];
    lds[1104 + t] = b2[t];
    lds[1120 + t] = b3[t];
    float s1 = g1[t] * rsqrtf(v1[t] + 1e-5f);
    lds[1136 + t] = s1;
    lds[1152 + t] = be1[t] - m1[t]*s1;
    float s2 = g2[t] * rsqrtf(v2[t] + 1e-5f);
    lds[1168 + t] = s2;
    lds[1184 + t] = be2[t] - m2[t]*s2;
  }
}

__device__ __forceinline__ void topk_insert(float (&s)[16], int (&si)[16], float d, int qi) {
  #pragma unroll
  for (int j = 15; j >= 1; --j) {
    bool c1 = d < s[j-1];
    bool c2 = d < s[j];
    float ns = c1 ? s[j-1] : (c2 ? d : s[j]);
    int  ni = c1 ? si[j-1] : (c2 ? qi : si[j]);
    s[j] = ns; si[j] = ni;
  }
  if (d < s[0]) { si[0] = qi; s[0] = d; }
}

__device__ __forceinline__ void mlp_and_store(const float* lds, const float2* spill, int t,
    const float* __restrict__ yat, float* __restrict__ out, int p)
{
  const float* W1t = lds;
  const float* W2t = lds + 320;
  const float* W3t = lds + 576;
  const float* sb1 = lds + 1088;
  const float* sb2 = lds + 1104;
  const float* sb3 = lds + 1120;
  const float* S1 = lds + 1136;
  const float* T1 = lds + 1152;
  const float* S2 = lds + 1168;
  const float* T2 = lds + 1184;

  float fx1[16], fx2[16];
  #pragma unroll
  for (int o = 0; o < 16; ++o) { fx1[o] = 0.0f; fx2[o] = 0.0f; }

  #pragma unroll 1
  for (int j = 0; j < 16; ++j) {
    float2 sv = spill[j*256 + t];
    float invd = 1.0f / sv.x;
    int id = __float_as_int(sv.y);
    const float4* a4 = (const float4*)(yat + ((size_t)id << 4));
    float4 q0 = a4[0], q1 = a4[1], q2 = a4[2], q3 = a4[3];
    float a[16];
    a[0]=q0.x; a[1]=q0.y; a[2]=q0.z; a[3]=q0.w;
    a[4]=q1.x; a[5]=q1.y; a[6]=q1.z; a[7]=q1.w;
    a[8]=q2.x; a[9]=q2.y; a[10]=q2.z; a[11]=q2.w;
    a[12]=q3.x; a[13]=q3.y; a[14]=q3.z; a[15]=q3.w;
    float h[16];
    #pragma unroll
    for (int o = 0; o < 16; ++o) {
      float acc = fmaf(invd, W1t[o*20 + 16], sb1[o]);
      #pragma unroll
      for (int i = 0; i < 16; ++i) acc = fmaf(a[i], W1t[o*20 + i], acc);
      acc = fmaxf(acc, 0.2f * acc);
      float hv = fmaf(acc, S1[o], T1[o]);
      h[o] = hv;
      fx1[o] += hv;
    }
    #pragma unroll
    for (int o = 0; o < 16; ++o) {
      float acc = sb2[o];
      #pragma unroll
      for (int i = 0; i < 16; ++i) acc = fmaf(h[i], W2t[o*16 + i], acc);
      acc = fmaxf(acc, 0.2f * acc);
      fx2[o] += fmaf(acc, S2[o], T2[o]);
    }
  }

  float res[16];
  #pragma unroll
  for (int o = 0; o < 16; ++o) {
    float acc = sb3[o];
    #pragma unroll
    for (int i = 0; i < 16; ++i) acc = fmaf(fx1[i], W3t[o*32 + i], acc);
    #pragma unroll
    for (int i = 0; i < 16; ++i) acc = fmaf(fx2[i], W3t[o*32 + 16 + i], acc);
    res[o] = acc;
  }
  float* op = out + ((size_t)p << 4);
  float4 r;
  r.x=res[0]; r.y=res[1]; r.z=res[2]; r.w=res[3];   ((float4*)op)[0] = r;
  r.x=res[4]; r.y=res[5]; r.z=res[6]; r.w=res[7];   ((float4*)op)[1] = r;
  r.x=res[8]; r.y=res[9]; r.z=res[10]; r.w=res[11]; ((float4*)op)[2] = r;
  r.x=res[12]; r.y=res[13]; r.z=res[14]; r.w=res[15];((float4*)op)[3] = r;
}

__global__ void __launch_bounds__(256) knn_mlp_fused_kernel(
    const float* __restrict__ x, const float* __restrict__ yat,
    const float* __restrict__ W1, const float* __restrict__ b1,
    const float* __restrict__ W2, const float* __restrict__ b2,
    const float* __restrict__ W3, const float* __restrict__ b3,
    const float* __restrict__ g1, const float* __restrict__ be1,
    const float* __restrict__ m1, const float* __restrict__ v1,
    const float* __restrict__ g2, const float* __restrict__ be2,
    const float* __restrict__ m2, const float* __restrict__ v2,
    const float4* __restrict__ ys4, const int* __restrict__ ystart,
    const int* __restrict__ xorder, float* __restrict__ out)
{
  __shared__ float lds[1200];
  __shared__ float2 spill[4096];
  int t = threadIdx.x;
  stage_weights(lds, t, W1,b1,W2,b2,W3,b3, g1,be1,m1,v1, g2,be2,m2,v2);
  __syncthreads();

  int gid = blockIdx.x * 256 + t;
  int p = xorder[gid];
  float xpx = x[3*p], xpy = x[3*p+1], xpz = x[3*p+2];
  int cx = cell_coord(xpx), cy = cell_coord(xpy), cz = cell_coord(xpz);

  float s[16]; int si[16];
  #pragma unroll
  for (int j = 0; j < 16; ++j) { s[j] = BIGF; si[j] = 0; }

  auto scan_row = [&](int gz, int gy, int xa, int xb) {
    int rowbase = (gz*NC + gy)*NC;
    int r0 = ystart[rowbase + xa];
    int r1 = ystart[rowbase + xb + 1];
    for (int i = r0; i < r1; ++i) {
      float4 q = ys4[i];
      float dx = xpx - q.x, dy = xpy - q.y, dz = xpz - q.z;
      float d = fmaf(dx, dx, fmaf(dy, dy, dz*dz));
      if (d < s[15]) topk_insert(s, si, d, __float_as_int(q.w));
    }
  };

  {
    int z0 = cz-1 < 0 ? 0 : cz-1, z1 = cz+1 > NC-1 ? NC-1 : cz+1;
    int y0 = cy-1 < 0 ? 0 : cy-1, y1 = cy+1 > NC-1 ? NC-1 : cy+1;
    int x0 = cx-1 < 0 ? 0 : cx-1, x1 = cx+1 > NC-1 ? NC-1 : cx+1;
    for (int gz = z0; gz <= z1; ++gz)
      for (int gy = y0; gy <= y1; ++gy)
        scan_row(gz, gy, x0, x1);
  }

  int R = 1;
  while (true) {
    float b = BIGF;
    if (cx - R >= 0)    b = fminf(b, xpx - (float)(cx-R)*CELLW);
    if (cx + R <= NC-2) b = fminf(b, (float)(cx+R+1)*CELLW - xpx);
    if (cy - R >= 0)    b = fminf(b, xpy - (float)(cy-R)*CELLW);
    if (cy + R <= NC-2) b = fminf(b, (float)(cy+R+1)*CELLW - xpy);
    if (cz - R >= 0)    b = fminf(b, xpz - (float)(cz-R)*CELLW);
    if (cz + R <= NC-2) b = fminf(b, (float)(cz+R+1)*CELLW - xpz);
    b = fmaxf(b - 1e-4f, 0.0f);
    if (s[15] <= b*b || R >= NC) break;
    ++R;
    int z0 = cz-R < 0 ? 0 : cz-R, z1 = cz+R > NC-1 ? NC-1 : cz+R;
    int y0 = cy-R < 0 ? 0 : cy-R, y1 = cy+R > NC-1 ? NC-1 : cy+R;
    int x0 = cx-R < 0 ? 0 : cx-R, x1 = cx+R > NC-1 ? NC-1 : cx+R;
    for (int gz = z0; gz <= z1; ++gz) {
      int dzz = gz - cz; if (dzz < 0) dzz = -dzz;
      for (int gy = y0; gy <= y1; ++gy) {
        int dyy = gy - cy; if (dyy < 0) dyy = -dyy;
        if (dzz == R || dyy == R) {
          scan_row(gz, gy, x0, x1);
        } else {
          if (cx - R >= 0)    scan_row(gz, gy, cx-R, cx-R);
          if (cx + R <= NC-1) scan_row(gz, gy, cx+R, cx+R);
        }
      }
    }
  }

  #pragma unroll
  for (int j = 0; j < 16; ++j) spill[j*256 + t] = make_float2(s[j], __int_as_float(si[j]));
  mlp_and_store(lds, spill, t, yat, out, p);
}

// ---- fallback 2: brute force (no workspace needed) ----
__global__ void __launch_bounds__(256) brute_kernel(
    const float* __restrict__ x, const float* __restrict__ y, const float* __restrict__ yat,
    const float* __restrict__ W1, const float* __restrict__ b1,
    const float* __restrict__ W2, const float* __restrict__ b2,
    const float* __restrict__ W3, const float* __restrict__ b3,
    const float* __restrict__ g1, const float* __restrict__ be1,
    const float* __restrict__ m1, const float* __restrict__ v1,
    const float* __restrict__ g2, const float* __restrict__ be2,
    const float* __restrict__ m2, const float* __restrict__ v2,
    float* __restrict__ out)
{
  __shared__ float lds[1200];
  __shared__ float2 spill[4096];
  __shared__ float4 ybuf[1024];
  int t = threadIdx.x;
  stage_weights(lds, t, W1,b1,W2,b2,W3,b3, g1,be1,m1,v1, g2,be2,m2,v2);

  int gid = blockIdx.x * 256 + t;
  float xpx = x[3*gid], xpy = x[3*gid+1], xpz = x[3*gid+2];
  float s[16]; int si[16];
  #pragma unroll
  for (int j = 0; j < 16; ++j) { s[j] = BIGF; si[j] = 0; }

  for (int base = 0; base < M_PTS; base += 1024) {
    int nload = M_PTS - base; if (nload > 1024) nload = 1024;
    __syncthreads();
    for (int k = t; k < nload; k += 256) {
      int i = base + k;
      ybuf[k] = make_float4(y[3*i], y[3*i+1], y[3*i+2], __int_as_float(i));
    }
    __syncthreads();
    for (int i2 = 0; i2 < nload; ++i2) {
      float4 q = ybuf[i2];
      float dx = xpx - q.x, dy = xpy - q.y, dz = xpz - q.z;
      float d = fmaf(dx, dx, fmaf(dy, dy, dz*dz));
      if (d < s[15]) topk_insert(s, si, d, __float_as_int(q.w));
    }
  }

  #pragma unroll
  for (int j = 0; j < 16; ++j) spill[j*256 + t] = make_float2(s[j], __int_as_float(si[j]));
  mlp_and_store(lds, spill, t, yat, out, gid);
}

extern "C" void kernel_launch(void* const* d_in, const int* in_sizes, int n_in,
                              void* d_out, int out_size, void* d_ws, size_t ws_size,
                              hipStream_t stream) {
  const float* x   = (const float*)d_in[0];
  const float* y   = (const float*)d_in[1];
  const float* yat = (const float*)d_in[2];
  const float* W1  = (const float*)d_in[5];
  const float* b1  = (const float*)d_in[6];
  const float* W2  = (const float*)d_in[7];
  const float* b2  = (const float*)d_in[8];
  const float* W3  = (const float*)d_in[9];
  const float* b3  = (const float*)d_in[10];
  const float* g1  = (const float*)d_in[11];
  const float* be1 = (const float*)d_in[12];
  const float* m1  = (const float*)d_in[13];
  const float* v1  = (const float*)d_in[14];
  const float* g2  = (const float*)d_in[15];
  const float* be2 = (const float*)d_in[16];
  const float* m2  = (const float*)d_in[17];
  const float* v2  = (const float*)d_in[18];
  float* out = (float*)d_out;

  // split-path ws layout (bytes):
  //   ys4    @ 0       : 320000
  //   xs4    @ 320000  : 1310720   (N float4: coords + orig idx)
  //   xorder @ 1630720 : 327680
  //   pi     @ 1958400 : 2621440   (N*16 u16, [gid][j])
  //   ycnt   @ 4579840 : 8800
  //   xcnt   @ 4588640 : 8800
  //   ystart @ 4597440 : 8800
  //   ycur   @ 4606240 : 8800
  //   xstart @ 4615040 : 8800
  //   xcur   @ 4623840 : 8800
  //   ntasks @ 4632640 : 16        (zeroed each call)
  //   tasks  @ 4632656 : 29280     -> end 4661936
  const size_t WS_SPLIT = 4661936;
  const size_t WS_FUSED = 700480;

  if (ws_size >= WS_SPLIT) {
    char* ws = (char*)d_ws;
    float4* ys4 = (float4*)(ws);
    float4* xs4 = (float4*)(ws + 320000);
    int* xorder = (int*)(ws + 1630720);
    unsigned short* pi = (unsigned short*)(ws + 1958400);
    int* ycnt   = (int*)(ws + 4579840);
    int* xcnt   = (int*)(ws + 4588640);
    int* ystart = (int*)(ws + 4597440);
    int* ycur   = (int*)(ws + 4606240);
    int* xstart = (int*)(ws + 4615040);
    int* xcur   = (int*)(ws + 4623840);
    int* ntasks = (int*)(ws + 4632640);
    int* tasks  = (int*)(ws + 4632656);

    hipMemsetAsync(ws + 4579840, 0, 17600, stream);   // ycnt + xcnt
    hipMemsetAsync(ws + 4632640, 0, 16, stream);      // ntasks
    int grid_mn = (M_PTS + N_PTS + 255) / 256;
    hist_both_kernel<<<grid_mn, 256, 0, stream>>>(y, x, ycnt, xcnt);
    scan2_kernel<<<2, 1024, 0, stream>>>(ycnt, ystart, ycur, xcnt, xstart, xcur);
    scatter_both_kernel<<<grid_mn, 256, 0, stream>>>(y, x, ycur, xcur, ys4, xorder, xs4);
    build_tasks_kernel<<<(NCELLS+255)/256, 256, 0, stream>>>(xstart, tasks, ntasks);
    // no sortcell: key-space selection is scan-order independent
    knn_cell_kernel<<<MAX_TASKS/WPB, 256, 0, stream>>>(xs4, ys4, ystart, xstart,
        tasks, ntasks, pi);
    mlp_kernel<<<(N_PTS*16)/256, 256, 0, stream>>>(yat, xs4, y, W1,b1,W2,b2,W3,b3,
        g1,be1,m1,v1, g2,be2,m2,v2, pi, out);
  } else if (ws_size >= WS_FUSED) {
    char* ws = (char*)d_ws;
    float4* ys4 = (float4*)(ws);
    int* xorder = (int*)(ws + 320000);
    int* ycnt   = (int*)(ws + 647680);
    int* xcnt   = (int*)(ws + 656480);
    int* ystart = (int*)(ws + 665280);
    int* ycur   = (int*)(ws + 674080);
    int* xstart = (int*)(ws + 682880);
    int* xcur   = (int*)(ws + 691680);

    hipMemsetAsync(ws + 647680, 0, 17588, stream);
    int grid_mn = (M_PTS + N_PTS + 255) / 256;
    hist_both_kernel<<<grid_mn, 256, 0, stream>>>(y, x, ycnt, xcnt);
    scan2_kernel<<<2, 1024, 0, stream>>>(ycnt, ystart, ycur, xcnt, xstart, xcur);
    scatter_both_kernel<<<grid_mn, 256, 0, stream>>>(y, x, ycur, xcur, ys4, xorder, nullptr);
    sortcell_kernel<<<(NCELLS+255)/256, 256, 0, stream>>>(ys4, ystart);
    knn_mlp_fused_kernel<<<N_PTS/256, 256, 0, stream>>>(x, yat, W1,b1,W2,b2,W3,b3,
        g1,be1,m1,v1, g2,be2,m2,v2, ys4, ystart, xorder, out);
  } else {
    brute_kernel<<<N_PTS/256, 256, 0, stream>>>(x, y, yat, W1,b1,W2,b2,W3,b3,
        g1,be1,m1,v1, g2,be2,m2,v2, out);
  }
}

// Round 13
// 115.308 us; speedup vs baseline: 1.6392x; 1.0609x over previous
//
#include <hip/hip_runtime.h>

#define N_PTS 81920
#define M_PTS 20000
#define NC 14
#define NCELLS 2744
#define CELLW 0.7142857143f
#define INVCELL 1.4f
#define BIGF 3.0e38f
#define CAP_STAGE 264
#define PPC 16   // points per task (x 4 subs = 64 lanes)
#define WPB 4    // wave-tasks per 256-thread workgroup
#define MAX_TASKS 7880   // >= NCELLS + N_PTS/PPC, multiple of WPB

__device__ __forceinline__ int clampi(int v, int lo, int hi) {
  return v < lo ? lo : (v > hi ? hi : v);
}
__device__ __forceinline__ int cell_coord(float p) {
  return clampi((int)(p * INVCELL), 0, NC - 1);
}
__device__ __forceinline__ float floorpack(float d) {
  return __uint_as_float(__float_as_uint(d) & 0xFFFF8000u);
}

// ---- setup kernels ----

__global__ void hist_both_kernel(const float* __restrict__ y, const float* __restrict__ x,
                                 int* __restrict__ ycnt, int* __restrict__ xcnt) {
  int i = blockIdx.x * blockDim.x + threadIdx.x;
  if (i < M_PTS) {
    int c = (cell_coord(y[3*i+2])*NC + cell_coord(y[3*i+1]))*NC + cell_coord(y[3*i]);
    atomicAdd(&ycnt[c], 1);
  } else {
    int j = i - M_PTS;
    if (j < N_PTS) {
      int c = (cell_coord(x[3*j+2])*NC + cell_coord(x[3*j+1]))*NC + cell_coord(x[3*j]);
      atomicAdd(&xcnt[c], 1);
    }
  }
}

// block 0: scan ycnt -> ystart/ycur.  block 1: scan xcnt -> xstart/xcur AND
// build the dense task list deterministically (second prefix over ceil(cnt/PPC)).
__global__ void scan2_kernel(const int* __restrict__ ycnt, int* __restrict__ ystart, int* __restrict__ ycur,
                             const int* __restrict__ xcnt, int* __restrict__ xstart, int* __restrict__ xcur,
                             int* __restrict__ tasks, int* __restrict__ ntasks) {
  const int* cnt = (blockIdx.x == 0) ? ycnt : xcnt;
  int* start     = (blockIdx.x == 0) ? ystart : xstart;
  int* cursor    = (blockIdx.x == 0) ? ycur : xcur;
  __shared__ int tmp[1024];
  int tid = threadIdx.x;
  int chunk = (NCELLS + 1023) >> 10;
  int base = tid * chunk;
  int sum = 0;
  for (int k = 0; k < chunk; ++k) {
    int j = base + k;
    if (j < NCELLS) sum += cnt[j];
  }
  tmp[tid] = sum;
  __syncthreads();
  for (int off = 1; off < 1024; off <<= 1) {
    int v = (tid >= off) ? tmp[tid - off] : 0;
    __syncthreads();
    tmp[tid] += v;
    __syncthreads();
  }
  int run = tmp[tid] - sum;
  for (int k = 0; k < chunk; ++k) {
    int j = base + k;
    if (j < NCELLS) { start[j] = run; cursor[j] = run; run += cnt[j]; }
  }
  if (tid == 1023) start[NCELLS] = tmp[1023];

  if (blockIdx.x == 1) {
    int tsum = 0;
    for (int k = 0; k < chunk; ++k) {
      int j = base + k;
      if (j < NCELLS) tsum += (cnt[j] + PPC - 1) / PPC;
    }
    __syncthreads();          // tmp reuse
    tmp[tid] = tsum;
    __syncthreads();
    for (int off = 1; off < 1024; off <<= 1) {
      int v = (tid >= off) ? tmp[tid - off] : 0;
      __syncthreads();
      tmp[tid] += v;
      __syncthreads();
    }
    int trun = tmp[tid] - tsum;
    for (int k = 0; k < chunk; ++k) {
      int j = base + k;
      if (j < NCELLS) {
        int nch = (cnt[j] + PPC - 1) / PPC;
        for (int q2 = 0; q2 < nch; ++q2) tasks[trun++] = (q2 << 12) | j;   // j < 4096
      }
    }
    if (tid == 1023) ntasks[0] = tmp[1023];
  }
}

__global__ void scatter_both_kernel(const float* __restrict__ y, const float* __restrict__ x,
                                    int* __restrict__ ycur, int* __restrict__ xcur,
                                    float4* __restrict__ ys4, int* __restrict__ xorder,
                                    float4* __restrict__ xs4, float4* __restrict__ y4) {
  int i = blockIdx.x * blockDim.x + threadIdx.x;
  if (i < M_PTS) {
    float px = y[3*i], py = y[3*i+1], pz = y[3*i+2];
    if (y4) y4[i] = make_float4(px, py, pz, 0.0f);   // original-order copy for MLP
    int c = (cell_coord(pz)*NC + cell_coord(py))*NC + cell_coord(px);
    int pos = atomicAdd(&ycur[c], 1);
    ys4[pos] = make_float4(px, py, pz, __int_as_float(i));
  } else {
    int j = i - M_PTS;
    if (j < N_PTS) {
      float px = x[3*j], py = x[3*j+1], pz = x[3*j+2];
      int c = (cell_coord(pz)*NC + cell_coord(py))*NC + cell_coord(px);
      int pos = atomicAdd(&xcur[c], 1);
      xorder[pos] = j;
      if (xs4) xs4[pos] = make_float4(px, py, pz, __int_as_float(j));
    }
  }
}

// (fused/brute fallback only) determinism: in-cell sort by original index
__global__ void sortcell_kernel(float4* __restrict__ ys4, const int* __restrict__ ystart) {
  int c = blockIdx.x * blockDim.x + threadIdx.x;
  if (c >= NCELLS) return;
  int r0 = ystart[c], r1 = ystart[c+1];
  for (int i = r0 + 1; i < r1; ++i) {
    float4 v = ys4[i];
    int key = __float_as_int(v.w);
    int j = i - 1;
    while (j >= r0 && __float_as_int(ys4[j].w) > key) { ys4[j+1] = ys4[j]; --j; }
    ys4[j+1] = v;
  }
}

// sort a bitonic 16-sequence ascending (valid only for bitonic input)
__device__ __forceinline__ void bitonic_sort16(float (&d)[16]) {
  #define CE(a,b) { float lo=fminf(d[a],d[b]); float hi=fmaxf(d[a],d[b]); d[a]=lo; d[b]=hi; }
  CE(0,8) CE(1,9) CE(2,10) CE(3,11) CE(4,12) CE(5,13) CE(6,14) CE(7,15)
  CE(0,4) CE(1,5) CE(2,6) CE(3,7) CE(8,12) CE(9,13) CE(10,14) CE(11,15)
  CE(0,2) CE(1,3) CE(4,6) CE(5,7) CE(8,10) CE(9,11) CE(12,14) CE(13,15)
  CE(0,1) CE(2,3) CE(4,5) CE(6,7) CE(8,9) CE(10,11) CE(12,13) CE(14,15)
  #undef CE
}

// branchless sorted insert into ascending 16-list; ~31 VALU ops
__device__ __forceinline__ void ins16(float (&s)[16], float k) {
  #pragma unroll
  for (int j = 15; j >= 1; --j) s[j] = fminf(fmaxf(s[j-1], k), s[j]);
  s[0] = fminf(s[0], k);
}

// ---- split path kernel A: kNN; dense task list, 4 wave-tasks per WG ----
// Each wave owns one (cell,chunk) task and a private LDS slice; no block
// barriers (per-wave staging + wave-local waitcnt fence). TPP=4 within the wave.
// key = (d_bits & 0xFFFF8000) | id -> exact in key space, scan-order
// independent, replay-deterministic.
__global__ void __launch_bounds__(256) knn_cell_kernel(
    const float4* __restrict__ xs4,
    const float4* __restrict__ ys4, const int* __restrict__ ystart,
    const int* __restrict__ xstart,
    const int* __restrict__ tasks, const int* __restrict__ ntasks,
    unsigned short* __restrict__ pi)
{
  __shared__ float4 cand_all[WPB][CAP_STAGE];
  int wid = threadIdx.x >> 6;
  int tid = threadIdx.x & 63;           // lane within wave
  int ti = blockIdx.x * WPB + wid;      // fixed grid = MAX_TASKS/WPB blocks
  if (ti >= ntasks[0]) return;          // wave-uniform; no barriers to violate
  int task = tasks[ti];
  int c = task & 4095, chunk = task >> 12;
  int cbeg = xstart[c];
  int cend = xstart[c+1];
  int pbeg = cbeg + chunk*PPC;
  int pend = min(cend, pbeg + PPC);

  float4* cand = cand_all[wid];

  int ccx = c % NC, ccy = (c / NC) % NC, ccz = c / (NC*NC);
  int x0 = ccx-1 < 0 ? 0 : ccx-1, x1 = ccx+1 > NC-1 ? NC-1 : ccx+1;
  int y0 = ccy-1 < 0 ? 0 : ccy-1, y1 = ccy+1 > NC-1 ? NC-1 : ccy+1;
  int z0 = ccz-1 < 0 ? 0 : ccz-1, z1 = ccz+1 > NC-1 ? NC-1 : ccz+1;

  // stage clamped 3x3x3 region into this wave's slice (rows contiguous in ys4)
  int off = 0, nst = 0; bool ovf = false;
  for (int gz = z0; gz <= z1; ++gz) {
    for (int gy = y0; gy <= y1; ++gy) {
      int rowbase = (gz*NC + gy)*NC;
      int r0 = ystart[rowbase + x0];
      int r1 = ystart[rowbase + x1 + 1];
      int len = r1 - r0;
      if (!ovf && off + len <= CAP_STAGE) {
        for (int k = tid; k < len; k += 64) cand[off + k] = ys4[r0 + k];
        off += len; ++nst;
      } else ovf = true;
    }
  }
  int L = off;
  // wave-local fence: all global loads landed, all LDS writes visible to wave
  asm volatile("s_waitcnt vmcnt(0) lgkmcnt(0)" ::: "memory");

  int g = tid >> 2, sub = tid & 3;
  int pidx = pbeg + g;
  bool active = pidx < pend;
  int gid = active ? pidx : (pend - 1);   // inactive groups dup last point
  float4 xq = xs4[gid];
  float xpx = xq.x, xpy = xq.y, xpz = xq.z;

  float s[16];
  #pragma unroll
  for (int j = 0; j < 16; ++j) s[j] = BIGF;

  auto packkey = [&](float4 q) -> float {
    float dx = xpx - q.x, dy = xpy - q.y, dz = xpz - q.z;
    float d = fmaf(dx, dx, fmaf(dy, dy, dz*dz));
    unsigned kb = (__float_as_uint(d) & 0xFFFF8000u) | (__float_as_uint(q.w) & 0x7FFFu);
    return __uint_as_float(kb);
  };

  // exact union top-16 across the 4 subs of this group (identical in all 4 lanes)
  auto merged16 = [&](float (&u)[16]) {
    float cb[16];
    #pragma unroll
    for (int i = 0; i < 16; ++i) cb[i] = fminf(s[i], __shfl_xor(s[15-i], 1));
    bitonic_sort16(cb);
    #pragma unroll
    for (int i = 0; i < 16; ++i) u[i] = fminf(cb[i], __shfl_xor(cb[15-i], 2));
    bitonic_sort16(u);
  };

  { // scan staged candidates: stride-4 sub partition, broadcast LDS reads
    int i = sub;
    for (; i + 4 < L; i += 8) {
      float4 q0 = cand[i], q1 = cand[i+4];
      float k0 = packkey(q0), k1 = packkey(q1);
      ins16(s, k0); ins16(s, k1);
    }
    for (; i < L; i += 4) ins16(s, packkey(cand[i]));
  }

  auto scan_row_g = [&](int xa, int xb, int rowbase) {
    int r0 = ystart[rowbase + xa];
    int r1 = ystart[rowbase + xb + 1];
    int i = r0 + sub;
    for (; i + 4 < r1; i += 8) {
      float4 q0 = ys4[i], q1 = ys4[i+4];
      float k0 = packkey(q0), k1 = packkey(q1);
      ins16(s, k0); ins16(s, k1);
    }
    for (; i < r1; i += 4) ins16(s, packkey(ys4[i]));
  };

  if (ovf) { // staged prefix only; scan remaining region rows from global (rare)
    int cnt2 = 0;
    for (int gz = z0; gz <= z1; ++gz)
      for (int gy = y0; gy <= y1; ++gy) {
        if (cnt2 >= nst) scan_row_g(x0, x1, (gz*NC + gy)*NC);
        ++cnt2;
      }
  }

  // ring expansion (exact in key space) with row/cell culling vs merged 16th
  float u[16];
  merged16(u);
  float s15m = u[15];
  int R = 1;
  while (true) {
    float b = BIGF;
    if (ccx - R >= 0)    b = fminf(b, xpx - (float)(ccx-R)*CELLW);
    if (ccx + R <= NC-2) b = fminf(b, (float)(ccx+R+1)*CELLW - xpx);
    if (ccy - R >= 0)    b = fminf(b, xpy - (float)(ccy-R)*CELLW);
    if (ccy + R <= NC-2) b = fminf(b, (float)(ccy+R+1)*CELLW - xpy);
    if (ccz - R >= 0)    b = fminf(b, xpz - (float)(ccz-R)*CELLW);
    if (ccz + R <= NC-2) b = fminf(b, (float)(ccz+R+1)*CELLW - xpz);
    b = fmaxf(b - 1e-4f, 0.0f);          // conservative vs binning rounding
    if (s15m <= floorpack(b*b) || R >= NC) break;
    ++R;
    int z0r = ccz-R < 0 ? 0 : ccz-R, z1r = ccz+R > NC-1 ? NC-1 : ccz+R;
    int y0r = ccy-R < 0 ? 0 : ccy-R, y1r = ccy+R > NC-1 ? NC-1 : ccy+R;
    int x0r = ccx-R < 0 ? 0 : ccx-R, x1r = ccx+R > NC-1 ? NC-1 : ccx+R;
    for (int gz = z0r; gz <= z1r; ++gz) {
      int dzz = gz - ccz; if (dzz < 0) dzz = -dzz;
      float gapz = (gz > ccz) ? ((float)gz*CELLW - xpz)
                 : ((gz < ccz) ? (xpz - (float)(gz+1)*CELLW) : 0.0f);
      gapz = fmaxf(gapz - 1e-4f, 0.0f);
      float gz2 = gapz * gapz;
      for (int gy = y0r; gy <= y1r; ++gy) {
        int dyy = gy - ccy; if (dyy < 0) dyy = -dyy;
        float gapy = (gy > ccy) ? ((float)gy*CELLW - xpy)
                   : ((gy < ccy) ? (xpy - (float)(gy+1)*CELLW) : 0.0f);
        gapy = fmaxf(gapy - 1e-4f, 0.0f);
        float rowd2 = fmaf(gapy, gapy, gz2);
        if (floorpack(rowd2) >= s15m) continue;   // row can't beat union 16th
        int rowbase = (gz*NC + gy)*NC;
        if (dzz == R || dyy == R) {
          scan_row_g(x0r, x1r, rowbase);
        } else {
          if (ccx - R >= 0) {
            float gapx = fmaxf(xpx - (float)(ccx-R+1)*CELLW - 1e-4f, 0.0f);
            if (floorpack(fmaf(gapx, gapx, rowd2)) < s15m)
              scan_row_g(ccx-R, ccx-R, rowbase);
          }
          if (ccx + R <= NC-1) {
            float gapx = fmaxf((float)(ccx+R)*CELLW - xpx - 1e-4f, 0.0f);
            if (floorpack(fmaf(gapx, gapx, rowd2)) < s15m)
              scan_row_g(ccx+R, ccx+R, rowbase);
          }
        }
      }
    }
    merged16(u);
    s15m = u[15];
  }

  if (active) {  // each sub writes 4 u16 ids of the sorted union (8B store)
    float v0 = u[sub*4+0], v1 = u[sub*4+1], v2 = u[sub*4+2], v3 = u[sub*4+3];
    unsigned wlo = (__float_as_uint(v0) & 0x7FFFu) | ((__float_as_uint(v1) & 0x7FFFu) << 16);
    unsigned whi = (__float_as_uint(v2) & 0x7FFFu) | ((__float_as_uint(v3) & 0x7FFFu) << 16);
    uint2 W; W.x = wlo; W.y = whi;
    ((uint2*)pi)[gid*4 + sub] = W;
  }
}

// ---- split path kernel B: MLP, one lane per (point, neighbor) ----
template<int CTRL>
__device__ __forceinline__ float ror_add(float v) {
  int r = __builtin_amdgcn_update_dpp(0, __float_as_int(v), CTRL, 0xF, 0xF, true);
  return v + __int_as_float(r);
}
__device__ __forceinline__ float red16(float v) {
  v = ror_add<0x121>(v);   // row_ror:1
  v = ror_add<0x122>(v);   // row_ror:2
  v = ror_add<0x124>(v);   // row_ror:4
  v = ror_add<0x128>(v);   // row_ror:8
  return v;                // every lane of the 16-row holds the 16-lane sum
}

__global__ void __launch_bounds__(256) mlp_kernel(
    const float* __restrict__ yat, const float4* __restrict__ xs4, const float4* __restrict__ y4,
    const float* __restrict__ W1, const float* __restrict__ b1,
    const float* __restrict__ W2, const float* __restrict__ b2,
    const float* __restrict__ W3, const float* __restrict__ b3,
    const float* __restrict__ g1, const float* __restrict__ be1,
    const float* __restrict__ m1, const float* __restrict__ v1,
    const float* __restrict__ g2, const float* __restrict__ be2,
    const float* __restrict__ m2, const float* __restrict__ v2,
    const unsigned short* __restrict__ pi, float* __restrict__ out)
{
  int t = threadIdx.x;
  int o = t & 15;                              // lane's neighbor slot / out channel
  int gid = (blockIdx.x * 256 + t) >> 4;       // grid = N_PTS*16 threads
  float4 xq = xs4[gid];                        // broadcast within group
  int p = __float_as_int(xq.w);

  int id = (int)pi[gid*16 + o];                // 32B per group, coalesced
  // recompute exact squared distance (selection used truncated keys)
  float4 yq = y4[id];                          // one float4 gather
  float dx = xq.x - yq.x, dy = xq.y - yq.y, dz = xq.z - yq.z;
  float dist = fmaf(dx, dx, fmaf(dy, dy, dz*dz));
  float invd = 1.0f / dist;                    // feature = 1/(squared dist)

  const float4* a4 = (const float4*)(yat + ((size_t)id << 4));
  float4 q0 = a4[0], q1 = a4[1], q2 = a4[2], q3 = a4[3];
  float a[16];
  a[0]=q0.x; a[1]=q0.y; a[2]=q0.z; a[3]=q0.w;
  a[4]=q1.x; a[5]=q1.y; a[6]=q1.z; a[7]=q1.w;
  a[8]=q2.x; a[9]=q2.y; a[10]=q2.z; a[11]=q2.w;
  a[12]=q3.x; a[13]=q3.y; a[14]=q3.z; a[15]=q3.w;

  // layer 1 (+leaky+BN1); weight indices compile-time -> wave-uniform loads
  float h[16];
  #pragma unroll
  for (int oo = 0; oo < 16; ++oo) {
    float acc = fmaf(invd, W1[256 + oo], b1[oo]);
    #pragma unroll
    for (int i = 0; i < 16; ++i) acc = fmaf(a[i], W1[i*16 + oo], acc);
    acc = fmaxf(acc, 0.2f * acc);              // leaky_relu(0.2)
    float S = g1[oo] * rsqrtf(v1[oo] + 1e-5f);
    h[oo] = fmaf(acc - m1[oo], S, be1[oo]);    // BN1
  }

  // layer 2 (+leaky+BN2)
  float f2[16];
  #pragma unroll
  for (int oo = 0; oo < 16; ++oo) {
    float acc = b2[oo];
    #pragma unroll
    for (int i = 0; i < 16; ++i) acc = fmaf(h[i], W2[i*16 + oo], acc);
    acc = fmaxf(acc, 0.2f * acc);
    float S = g2[oo] * rsqrtf(v2[oo] + 1e-5f);
    f2[oo] = fmaf(acc - m2[oo], S, be2[oo]);
  }

  // final layer fused with cross-neighbor DPP reduction; lane owns channel o
  float acc = b3[o];
  #pragma unroll
  for (int i = 0; i < 16; ++i) acc = fmaf(red16(h[i]),  W3[i*16 + o], acc);
  #pragma unroll
  for (int i = 0; i < 16; ++i) acc = fmaf(red16(f2[i]), W3[(16 + i)*16 + o], acc);

  out[(size_t)p*16 + o] = acc;                 // 64B per group, coalesced
}

// ---- fallback 1: fused kernel (only if ws too small for split path) ----
__device__ __forceinline__ void stage_weights(float* lds, int t,
    const float* W1, const float* b1, const float* W2, const float* b2,
    const float* W3, const float* b3,
    const float* g1, const float* be1, const float* m1, const float* v1,
    const float* g2, const float* be2, const float* m2, const float* v2)
{
  for (int k = t; k < 272; k += 256) { int i = k >> 4, o = k & 15; lds[o*20 + i] = W1[k]; }
  for (int k = t; k < 256; k += 256) { int i = k >> 4, o = k & 15; lds[320 + o*16 + i] = W2[k]; }
  for (int k = t; k < 512; k += 256) { int i = k >> 4, o = k & 15; lds[576 + o*32 + i] = W3[k]; }
  if (t < 16) {
    lds[1088 + t] = b1[t];
    lds[1104 + t] = b2[t];
    lds[1120 + t] = b3[t];
    float s1 = g1[t] * rsqrtf(v1[t] + 1e-5f);
    lds[1136 + t] = s1;
    lds[1152 + t] = be1[t] - m1[t]*s1;
    float s2 = g2[t] * rsqrtf(v2[t] + 1e-5f);
    lds[1168 + t] = s2;
    lds[1184 + t] = be2[t] - m2[t]*s2;
  }
}

__device__ __forceinline__ void topk_insert(float (&s)[16], int (&si)[16], float d, int qi) {
  #pragma unroll
  for (int j = 15; j >= 1; --j) {
    bool c1 = d < s[j-1];
    bool c2 = d < s[j];
    float ns = c1 ? s[j-1] : (c2 ? d : s[j]);
    int  ni = c1 ? si[j-1] : (c2 ? qi : si[j]);
    s[j] = ns; si[j] = ni;
  }
  if (d < s[0]) { si[0] = qi; s[0] = d; }
}

__device__ __forceinline__ void mlp_and_store(const float* lds, const float2* spill, int t,
    const float* __restrict__ yat, float* __restrict__ out, int p)
{
  const float* W1t = lds;
  const float* W2t = lds + 320;
  const float* W3t = lds + 576;
  const float* sb1 = lds + 1088;
  const float* sb2 = lds + 1104;
  const float* sb3 = lds + 1120;
  const float* S1 = lds + 1136;
  const float* T1 = lds + 1152;
  const float* S2 = lds + 1168;
  const float* T2 = lds + 1184;

  float fx1[16], fx2[16];
  #pragma unroll
  for (int o = 0; o < 16; ++o) { fx1[o] = 0.0f; fx2[o] = 0.0f; }

  #pragma unroll 1
  for (int j = 0; j < 16; ++j) {
    float2 sv = spill[j*256 + t];
    float invd = 1.0f / sv.x;
    int id = __float_as_int(sv.y);
    const float4* a4 = (const float4*)(yat + ((size_t)id << 4));
    float4 q0 = a4[0], q1 = a4[1], q2 = a4[2], q3 = a4[3];
    float a[16];
    a[0]=q0.x; a[1]=q0.y; a[2]=q0.z; a[3]=q0.w;
    a[4]=q1.x; a[5]=q1.y; a[6]=q1.z; a[7]=q1.w;
    a[8]=q2.x; a[9]=q2.y; a[10]=q2.z; a[11]=q2.w;
    a[12]=q3.x; a[13]=q3.y; a[14]=q3.z; a[15]=q3.w;
    float h[16];
    #pragma unroll
    for (int o = 0; o < 16; ++o) {
      float acc = fmaf(invd, W1t[o*20 + 16], sb1[o]);
      #pragma unroll
      for (int i = 0; i < 16; ++i) acc = fmaf(a[i], W1t[o*20 + i], acc);
      acc = fmaxf(acc, 0.2f * acc);
      float hv = fmaf(acc, S1[o], T1[o]);
      h[o] = hv;
      fx1[o] += hv;
    }
    #pragma unroll
    for (int o = 0; o < 16; ++o) {
      float acc = sb2[o];
      #pragma unroll
      for (int i = 0; i < 16; ++i) acc = fmaf(h[i], W2t[o*16 + i], acc);
      acc = fmaxf(acc, 0.2f * acc);
      fx2[o] += fmaf(acc, S2[o], T2[o]);
    }
  }

  float res[16];
  #pragma unroll
  for (int o = 0; o < 16; ++o) {
    float acc = sb3[o];
    #pragma unroll
    for (int i = 0; i < 16; ++i) acc = fmaf(fx1[i], W3t[o*32 + i], acc);
    #pragma unroll
    for (int i = 0; i < 16; ++i) acc = fmaf(fx2[i], W3t[o*32 + 16 + i], acc);
    res[o] = acc;
  }
  float* op = out + ((size_t)p << 4);
  float4 r;
  r.x=res[0]; r.y=res[1]; r.z=res[2]; r.w=res[3];   ((float4*)op)[0] = r;
  r.x=res[4]; r.y=res[5]; r.z=res[6]; r.w=res[7];   ((float4*)op)[1] = r;
  r.x=res[8]; r.y=res[9]; r.z=res[10]; r.w=res[11]; ((float4*)op)[2] = r;
  r.x=res[12]; r.y=res[13]; r.z=res[14]; r.w=res[15];((float4*)op)[3] = r;
}

__global__ void __launch_bounds__(256) knn_mlp_fused_kernel(
    const float* __restrict__ x, const float* __restrict__ yat,
    const float* __restrict__ W1, const float* __restrict__ b1,
    const float* __restrict__ W2, const float* __restrict__ b2,
    const float* __restrict__ W3, const float* __restrict__ b3,
    const float* __restrict__ g1, const float* __restrict__ be1,
    const float* __restrict__ m1, const float* __restrict__ v1,
    const float* __restrict__ g2, const float* __restrict__ be2,
    const float* __restrict__ m2, const float* __restrict__ v2,
    const float4* __restrict__ ys4, const int* __restrict__ ystart,
    const int* __restrict__ xorder, float* __restrict__ out)
{
  __shared__ float lds[1200];
  __shared__ float2 spill[4096];
  int t = threadIdx.x;
  stage_weights(lds, t, W1,b1,W2,b2,W3,b3, g1,be1,m1,v1, g2,be2,m2,v2);
  __syncthreads();

  int gid = blockIdx.x * 256 + t;
  int p = xorder[gid];
  float xpx = x[3*p], xpy = x[3*p+1], xpz = x[3*p+2];
  int cx = cell_coord(xpx), cy = cell_coord(xpy), cz = cell_coord(xpz);

  float s[16]; int si[16];
  #pragma unroll
  for (int j = 0; j < 16; ++j) { s[j] = BIGF; si[j] = 0; }

  auto scan_row = [&](int gz, int gy, int xa, int xb) {
    int rowbase = (gz*NC + gy)*NC;
    int r0 = ystart[rowbase + xa];
    int r1 = ystart[rowbase + xb + 1];
    for (int i = r0; i < r1; ++i) {
      float4 q = ys4[i];
      float dx = xpx - q.x, dy = xpy - q.y, dz = xpz - q.z;
      float d = fmaf(dx, dx, fmaf(dy, dy, dz*dz));
      if (d < s[15]) topk_insert(s, si, d, __float_as_int(q.w));
    }
  };

  {
    int z0 = cz-1 < 0 ? 0 : cz-1, z1 = cz+1 > NC-1 ? NC-1 : cz+1;
    int y0 = cy-1 < 0 ? 0 : cy-1, y1 = cy+1 > NC-1 ? NC-1 : cy+1;
    int x0 = cx-1 < 0 ? 0 : cx-1, x1 = cx+1 > NC-1 ? NC-1 : cx+1;
    for (int gz = z0; gz <= z1; ++gz)
      for (int gy = y0; gy <= y1; ++gy)
        scan_row(gz, gy, x0, x1);
  }

  int R = 1;
  while (true) {
    float b = BIGF;
    if (cx - R >= 0)    b = fminf(b, xpx - (float)(cx-R)*CELLW);
    if (cx + R <= NC-2) b = fminf(b, (float)(cx+R+1)*CELLW - xpx);
    if (cy - R >= 0)    b = fminf(b, xpy - (float)(cy-R)*CELLW);
    if (cy + R <= NC-2) b = fminf(b, (float)(cy+R+1)*CELLW - xpy);
    if (cz - R >= 0)    b = fminf(b, xpz - (float)(cz-R)*CELLW);
    if (cz + R <= NC-2) b = fminf(b, (float)(cz+R+1)*CELLW - xpz);
    b = fmaxf(b - 1e-4f, 0.0f);
    if (s[15] <= b*b || R >= NC) break;
    ++R;
    int z0 = cz-R < 0 ? 0 : cz-R, z1 = cz+R > NC-1 ? NC-1 : cz+R;
    int y0 = cy-R < 0 ? 0 : cy-R, y1 = cy+R > NC-1 ? NC-1 : cy+R;
    int x0 = cx-R < 0 ? 0 : cx-R, x1 = cx+R > NC-1 ? NC-1 : cx+R;
    for (int gz = z0; gz <= z1; ++gz) {
      int dzz = gz - cz; if (dzz < 0) dzz = -dzz;
      for (int gy = y0; gy <= y1; ++gy) {
        int dyy = gy - cy; if (dyy < 0) dyy = -dyy;
        if (dzz == R || dyy == R) {
          scan_row(gz, gy, x0, x1);
        } else {
          if (cx - R >= 0)    scan_row(gz, gy, cx-R, cx-R);
          if (cx + R <= NC-1) scan_row(gz, gy, cx+R, cx+R);
        }
      }
    }
  }

  #pragma unroll
  for (int j = 0; j < 16; ++j) spill[j*256 + t] = make_float2(s[j], __int_as_float(si[j]));
  mlp_and_store(lds, spill, t, yat, out, p);
}

// ---- fallback 2: brute force (no workspace needed) ----
__global__ void __launch_bounds__(256) brute_kernel(
    const float* __restrict__ x, const float* __restrict__ y, const float* __restrict__ yat,
    const float* __restrict__ W1, const float* __restrict__ b1,
    const float* __restrict__ W2, const float* __restrict__ b2,
    const float* __restrict__ W3, const float* __restrict__ b3,
    const float* __restrict__ g1, const float* __restrict__ be1,
    const float* __restrict__ m1, const float* __restrict__ v1,
    const float* __restrict__ g2, const float* __restrict__ be2,
    const float* __restrict__ m2, const float* __restrict__ v2,
    float* __restrict__ out)
{
  __shared__ float lds[1200];
  __shared__ float2 spill[4096];
  __shared__ float4 ybuf[1024];
  int t = threadIdx.x;
  stage_weights(lds, t, W1,b1,W2,b2,W3,b3, g1,be1,m1,v1, g2,be2,m2,v2);

  int gid = blockIdx.x * 256 + t;
  float xpx = x[3*gid], xpy = x[3*gid+1], xpz = x[3*gid+2];
  float s[16]; int si[16];
  #pragma unroll
  for (int j = 0; j < 16; ++j) { s[j] = BIGF; si[j] = 0; }

  for (int base = 0; base < M_PTS; base += 1024) {
    int nload = M_PTS - base; if (nload > 1024) nload = 1024;
    __syncthreads();
    for (int k = t; k < nload; k += 256) {
      int i = base + k;
      ybuf[k] = make_float4(y[3*i], y[3*i+1], y[3*i+2], __int_as_float(i));
    }
    __syncthreads();
    for (int i2 = 0; i2 < nload; ++i2) {
      float4 q = ybuf[i2];
      float dx = xpx - q.x, dy = xpy - q.y, dz = xpz - q.z;
      float d = fmaf(dx, dx, fmaf(dy, dy, dz*dz));
      if (d < s[15]) topk_insert(s, si, d, __float_as_int(q.w));
    }
  }

  #pragma unroll
  for (int j = 0; j < 16; ++j) spill[j*256 + t] = make_float2(s[j], __int_as_float(si[j]));
  mlp_and_store(lds, spill, t, yat, out, gid);
}

extern "C" void kernel_launch(void* const* d_in, const int* in_sizes, int n_in,
                              void* d_out, int out_size, void* d_ws, size_t ws_size,
                              hipStream_t stream) {
  const float* x   = (const float*)d_in[0];
  const float* y   = (const float*)d_in[1];
  const float* yat = (const float*)d_in[2];
  const float* W1  = (const float*)d_in[5];
  const float* b1  = (const float*)d_in[6];
  const float* W2  = (const float*)d_in[7];
  const float* b2  = (const float*)d_in[8];
  const float* W3  = (const float*)d_in[9];
  const float* b3  = (const float*)d_in[10];
  const float* g1  = (const float*)d_in[11];
  const float* be1 = (const float*)d_in[12];
  const float* m1  = (const float*)d_in[13];
  const float* v1  = (const float*)d_in[14];
  const float* g2  = (const float*)d_in[15];
  const float* be2 = (const float*)d_in[16];
  const float* m2  = (const float*)d_in[17];
  const float* v2  = (const float*)d_in[18];
  float* out = (float*)d_out;

  // split-path ws layout (bytes):
  //   ys4    @ 0       : 320000
  //   y4     @ 320000  : 320000    (original-order y as float4)
  //   xs4    @ 640000  : 1310720
  //   xorder @ 1950720 : 327680
  //   pi     @ 2278400 : 2621440
  //   ycnt   @ 4899840 : 11008
  //   xcnt   @ 4910848 : 11008
  //   ystart @ 4921856 : 11008
  //   ycur   @ 4932864 : 11008
  //   xstart @ 4943872 : 11008
  //   xcur   @ 4954880 : 11008
  //   ntasks @ 4965888 : 16
  //   tasks  @ 4965904 : 31520     -> end 4997424
  const size_t WS_SPLIT = 4997424;
  const size_t WS_FUSED = 760000;

  if (ws_size >= WS_SPLIT) {
    char* ws = (char*)d_ws;
    float4* ys4 = (float4*)(ws);
    float4* y4  = (float4*)(ws + 320000);
    float4* xs4 = (float4*)(ws + 640000);
    int* xorder = (int*)(ws + 1950720);
    unsigned short* pi = (unsigned short*)(ws + 2278400);
    int* ycnt   = (int*)(ws + 4899840);
    int* xcnt   = (int*)(ws + 4910848);
    int* ystart = (int*)(ws + 4921856);
    int* ycur   = (int*)(ws + 4932864);
    int* xstart = (int*)(ws + 4943872);
    int* xcur   = (int*)(ws + 4954880);
    int* ntasks = (int*)(ws + 4965888);
    int* tasks  = (int*)(ws + 4965904);

    hipMemsetAsync(ws + 4899840, 0, 22016, stream);   // ycnt + xcnt
    int grid_mn = (M_PTS + N_PTS + 255) / 256;
    hist_both_kernel<<<grid_mn, 256, 0, stream>>>(y, x, ycnt, xcnt);
    scan2_kernel<<<2, 1024, 0, stream>>>(ycnt, ystart, ycur, xcnt, xstart, xcur,
                                         tasks, ntasks);
    scatter_both_kernel<<<grid_mn, 256, 0, stream>>>(y, x, ycur, xcur, ys4, xorder, xs4, y4);
    // no sortcell: key-space selection is scan-order independent
    knn_cell_kernel<<<MAX_TASKS/WPB, 256, 0, stream>>>(xs4, ys4, ystart, xstart,
        tasks, ntasks, pi);
    mlp_kernel<<<(N_PTS*16)/256, 256, 0, stream>>>(yat, xs4, y4, W1,b1,W2,b2,W3,b3,
        g1,be1,m1,v1, g2,be2,m2,v2, pi, out);
  } else if (ws_size >= WS_FUSED) {
    char* ws = (char*)d_ws;
    float4* ys4 = (float4*)(ws);
    int* xorder = (int*)(ws + 320000);
    int* ycnt   = (int*)(ws + 647680);
    int* xcnt   = (int*)(ws + 658688);
    int* ystart = (int*)(ws + 669696);
    int* ycur   = (int*)(ws + 680704);
    int* xstart = (int*)(ws + 691712);
    int* xcur   = (int*)(ws + 702720);
    int* tasks  = (int*)(ws + 713728);   // unused by fused path but scan2 writes it
    int* ntasks = (int*)(ws + 713728);   // overlap ok: fused path ignores tasks

    hipMemsetAsync(ws + 647680, 0, 22016, stream);
    int grid_mn = (M_PTS + N_PTS + 255) / 256;
    hist_both_kernel<<<grid_mn, 256, 0, stream>>>(y, x, ycnt, xcnt);
    // NOTE: scan2 writes tasks/ntasks; give it scratch that the fused path never reads.
    scan2_kernel<<<2, 1024, 0, stream>>>(ycnt, ystart, ycur, xcnt, xstart, xcur,
                                         tasks + 4, ntasks);
    scatter_both_kernel<<<grid_mn, 256, 0, stream>>>(y, x, ycur, xcur, ys4, xorder, nullptr, nullptr);
    sortcell_kernel<<<(NCELLS+255)/256, 256, 0, stream>>>(ys4, ystart);
    knn_mlp_fused_kernel<<<N_PTS/256, 256, 0, stream>>>(x, yat, W1,b1,W2,b2,W3,b3,
        g1,be1,m1,v1, g2,be2,m2,v2, ys4, ystart, xorder, out);
  } else {
    brute_kernel<<<N_PTS/256, 256, 0, stream>>>(x, y, yat, W1,b1,W2,b2,W3,b3,
        g1,be1,m1,v1, g2,be2,m2,v2, out);
  }
}